// Round 12
// baseline (2210.248 us; speedup 1.0000x reference)
//
#include <hip/hip_runtime.h>
#include <math.h>

#define BATCH 16
#define NPTS  2048
#define DIM   768
#define NCH   24      // 768 / 32 k-chunks

typedef unsigned long long ull;
typedef float f32x4 __attribute__((ext_vector_type(4)));
typedef short bf8 __attribute__((ext_vector_type(8)));          // 8 bf16 = 4 VGPR

// RNE fp32 -> bf16, returned as bits with low 16 zeroed (== bf2f(f2bf(x)) bit pattern)
__device__ __forceinline__ unsigned bfr(float x) {
  unsigned u = __float_as_uint(x);
  return (u + 0x7FFFu + ((u >> 16) & 1u)) & 0xFFFF0000u;
}
__device__ __forceinline__ unsigned short f2bf(float x) {
  unsigned u = __float_as_uint(x);
  u += 0x7FFFu + ((u >> 16) & 1u);
  return (unsigned short)(u >> 16);
}

// split 8 fp32 -> 3 bf16x8 fragments (RNE split-3; residuals exact by Sterbenz).
// Identical bit formula + element packing as the verified round-8/9/10 pipeline.
__device__ __forceinline__ void split8(const f32x4& v0, const f32x4& v1,
                                       bf8& o1, bf8& o2, bf8& o3) {
  float wv[8];
  wv[0] = v0[0]; wv[1] = v0[1]; wv[2] = v0[2]; wv[3] = v0[3];
  wv[4] = v1[0]; wv[5] = v1[1]; wv[6] = v1[2]; wv[7] = v1[3];
  union { unsigned u[4]; bf8 v; } p1, p2, p3;
#pragma unroll
  for (int j = 0; j < 8; j += 2) {
    float w0 = wv[j], w1 = wv[j + 1];
    unsigned a0 = bfr(w0); float r0 = w0 - __uint_as_float(a0);
    unsigned a1 = bfr(w1); float r1 = w1 - __uint_as_float(a1);
    unsigned b0 = bfr(r0); float q0 = r0 - __uint_as_float(b0);
    unsigned b1 = bfr(r1); float q1 = r1 - __uint_as_float(b1);
    p1.u[j >> 1] = (a0 >> 16) | (a1 & 0xFFFF0000u);
    p2.u[j >> 1] = (b0 >> 16) | (b1 & 0xFFFF0000u);
    p3.u[j >> 1] = (bfr(q0) >> 16) | (bfr(q1) & 0xFFFF0000u);
  }
  o1 = p1.v; o2 = p2.v; o3 = p3.v;
}

// ---------------- normalize: fn = f / max(||f||,1e-12), fp64 norm (fp32 output) ----------------
__global__ void normalize_k(const float* __restrict__ feat, float* __restrict__ fn, int cs) {
  const int rn = blockIdx.x;                 // ci*NPTS + n
  const int ci = rn >> 11, n = rn & (NPTS - 1);
  const float* src = feat + ((size_t)(cs + ci) * NPTS + n) * DIM;
  const int t = threadIdx.x;                 // 256 threads
  float f0 = src[t], f1 = src[t + 256], f2 = src[t + 512];
  double s = (double)f0 * (double)f0 + (double)f1 * (double)f1 + (double)f2 * (double)f2;
  for (int off = 32; off > 0; off >>= 1) s += __shfl_down(s, off);
  __shared__ double ps[4];
  __shared__ double rbc;
  const int lane = t & 63, wid = t >> 6;
  if (lane == 0) ps[wid] = s;
  __syncthreads();
  if (t == 0) {
    double tot = ps[0] + ps[1] + ps[2] + ps[3];
    rbc = fmax(sqrt(tot), 1e-12);
  }
  __syncthreads();
  const double r = rbc;
  float* dst = fn + ((size_t)ci * NPTS + n) * DIM;
  dst[t]       = (float)((double)f0 / r);
  dst[t + 256] = (float)((double)f1 / r);
  dst[t + 512] = (float)((double)f2 / r);
}

// ---------------- similarity: S = fn.fn^T via split-3 bf16 MFMA + 0.5*exp(-d2/1e4) ------------
// Upper-triangle 128x128 tiles (bx<=by); mirror_k fills the rest.
// Structure (round-11): raw fp32 staged straight to LDS with global_load_lds (width 16),
// double-buffered [2][128][32] per matrix = 64 KB total; ONE barrier per chunk; next-chunk
// loads issued right AFTER the barrier so their vmcnt drain (at the next barrier) lands
// ~2000 cy later, fully covered. Round 9/10 issued loads right BEFORE the barrier -> the
// implicit vmcnt(0) drain exposed full load latency every chunk (the m97 barrier-drain trap).
// fp32->bf16 split-3 happens IN REGISTERS after the fragment read (no bf16 LDS round-trip,
// no staging VGPRs/WAW chains). Bank uniformity via pre-swizzled GLOBAL source (16B-slot
// rotation pslot=(cslot+row&7)&7; LDS stays linear as global_load_lds requires).
// Same RNE bit formula + same MFMA order as rounds 8-10 -> S bit-identical.
__global__ __launch_bounds__(256, 1) void gemm_k(const float* __restrict__ fn,
                                                 const float* __restrict__ coords,
                                                 float* __restrict__ S, int cs) {
  if (blockIdx.x > blockIdx.y) return;       // symmetry: skip strictly-lower tiles
  const int ci = blockIdx.z;
  const int i0 = blockIdx.x * 128;
  const int j0 = blockIdx.y * 128;
  const int tid  = threadIdx.x;              // 256
  const int lane = tid & 63, w = tid >> 6;
  const int wr = (w >> 1) * 64, wc = (w & 1) * 64;   // wave quadrant
  const int lo = lane & 15, quad = lane >> 4;

  __shared__ float Ar[2][128][32];           // 32 KB (2 bufs), raw fp32, linear
  __shared__ float Br[2][128][32];           // 32 KB

  f32x4 aH[4][4], aM[4][4], aL[4][4];
#pragma unroll
  for (int tr = 0; tr < 4; ++tr)
#pragma unroll
    for (int tc = 0; tc < 4; ++tc) {
      aH[tr][tc] = (f32x4){0.f, 0.f, 0.f, 0.f};
      aM[tr][tc] = (f32x4){0.f, 0.f, 0.f, 0.f};
      aL[tr][tc] = (f32x4){0.f, 0.f, 0.f, 0.f};
    }

  const float* fb = fn + (size_t)ci * NPTS * DIM;
  // staging geometry: load i (0..3) of thread t covers LDS 16B-slot (i*256 + t):
  //   row = i*32 + (t>>3), pslot = t&7; global cslot = (pslot - (row&7)) & 7.
  const int trow  = tid >> 3;                // 0..31
  const int pslot = tid & 7;

  auto issue = [&](int p, int kc) {
#pragma unroll
    for (int i = 0; i < 4; ++i) {
      const int row   = i * 32 + trow;
      const int cslot = (pslot - (row & 7)) & 7;
      const float* ga = fb + (size_t)(i0 + row) * DIM + kc + cslot * 4;
      const float* gb = fb + (size_t)(j0 + row) * DIM + kc + cslot * 4;
      float* la = &Ar[p][0][0] + (size_t)(i * 256 + tid) * 4;
      float* lb = &Br[p][0][0] + (size_t)(i * 256 + tid) * 4;
      __builtin_amdgcn_global_load_lds((const __attribute__((address_space(1))) void*)ga,
                                       (__attribute__((address_space(3))) void*)la, 16, 0, 0);
      __builtin_amdgcn_global_load_lds((const __attribute__((address_space(1))) void*)gb,
                                       (__attribute__((address_space(3))) void*)lb, 16, 0, 0);
    }
  };

  issue(0, 0);                               // prologue: chunk 0 -> buf 0
  int p = 0;

#pragma unroll 1
  for (int c = 0; c < NCH; ++c) {
    __syncthreads();                         // chunk-c loads complete; prev compute done
    if (c + 1 < NCH) issue(p ^ 1, (c + 1) * 32);   // in flight across this chunk's compute

    // fragment reads (rotated slots) + in-register split-3, then MFMA.
    bf8 B0[4], B1[4], B2[4];
#pragma unroll
    for (int t = 0; t < 4; ++t) {
      const int r = wc + t * 16 + lo;
      const int x = r & 7;
      const int s0 = ((2 * quad + 0) + x) & 7;
      const int s1 = ((2 * quad + 1) + x) & 7;
      f32x4 v0 = *(const f32x4*)&Br[p][r][s0 * 4];
      f32x4 v1 = *(const f32x4*)&Br[p][r][s1 * 4];
      split8(v0, v1, B0[t], B1[t], B2[t]);
    }
#pragma unroll
    for (int tr = 0; tr < 4; ++tr) {
      const int r = wr + tr * 16 + lo;
      const int x = r & 7;
      const int s0 = ((2 * quad + 0) + x) & 7;
      const int s1 = ((2 * quad + 1) + x) & 7;
      f32x4 v0 = *(const f32x4*)&Ar[p][r][s0 * 4];
      f32x4 v1 = *(const f32x4*)&Ar[p][r][s1 * 4];
      bf8 A0, A1, A2;
      split8(v0, v1, A0, A1, A2);
#pragma unroll
      for (int tc = 0; tc < 4; ++tc) {
        aH[tr][tc] = __builtin_amdgcn_mfma_f32_16x16x32_bf16(A0, B0[tc], aH[tr][tc], 0, 0, 0);
        aM[tr][tc] = __builtin_amdgcn_mfma_f32_16x16x32_bf16(A0, B1[tc], aM[tr][tc], 0, 0, 0);
        aM[tr][tc] = __builtin_amdgcn_mfma_f32_16x16x32_bf16(A1, B0[tc], aM[tr][tc], 0, 0, 0);
        aL[tr][tc] = __builtin_amdgcn_mfma_f32_16x16x32_bf16(A0, B2[tc], aL[tr][tc], 0, 0, 0);
        aL[tr][tc] = __builtin_amdgcn_mfma_f32_16x16x32_bf16(A1, B1[tc], aL[tr][tc], 0, 0, 0);
        aL[tr][tc] = __builtin_amdgcn_mfma_f32_16x16x32_bf16(A2, B0[tc], aL[tr][tc], 0, 0, 0);
      }
    }
    p ^= 1;
  }

  // ---- probe the true C/D slot->(row,col) mapping (exact small ints in bf16/fp32) ----
  {
    const unsigned short encv = f2bf((float)lo);
    const unsigned short onev = f2bf(1.0f);
    bf8 enc, one;
#pragma unroll
    for (int t = 0; t < 8; ++t) { enc[t] = (short)encv; one[t] = (short)onev; }
    f32x4 z = (f32x4){0.f, 0.f, 0.f, 0.f};
    f32x4 d1 = __builtin_amdgcn_mfma_f32_16x16x32_bf16(enc, one, z, 0, 0, 0); // = 32*row
    f32x4 d2 = __builtin_amdgcn_mfma_f32_16x16x32_bf16(one, enc, z, 0, 0, 0); // = 32*col
    int rowp[4], colp[4];
#pragma unroll
    for (int r = 0; r < 4; ++r) {
      rowp[r] = ((int)(d1[r] * (1.0f / 32.0f))) & 15;
      colp[r] = ((int)(d2[r] * (1.0f / 32.0f))) & 15;
    }

    // epilogue: S = hi+mid+lo (fp64 sum) + 0.5*exp(-d2/1e4) (4th-order Taylor, exact regime)
    const float* cb = coords + (size_t)(cs + ci) * NPTS * 2;
    float* Sb = S + (size_t)ci * NPTS * NPTS;
#pragma unroll
    for (int r = 0; r < 4; ++r) {
      const int rl = rowp[r], cl = colp[r];
#pragma unroll
      for (int tr = 0; tr < 4; ++tr) {
        const int rowi = i0 + wr + tr * 16 + rl;
        float2 pi = *(const float2*)(cb + 2 * rowi);
        const double cix = pi.x, ciy = pi.y;
#pragma unroll
        for (int tc = 0; tc < 4; ++tc) {
          const int colj = j0 + wc + tc * 16 + cl;
          float2 pj = *(const float2*)(cb + 2 * colj);
          double dx = cix - (double)pj.x, dy = ciy - (double)pj.y;
          double x = (dx * dx + dy * dy) * (1.0 / 10000.0);
          double e = 1.0 - x * (1.0 - x * (0.5 - x * ((1.0 / 6.0) - x * (1.0 / 24.0))));
          double sem = (double)aH[tr][tc][r] + (double)aM[tr][tc][r] + (double)aL[tr][tc][r];
          Sb[(size_t)rowi * NPTS + colj] = (float)(sem + 0.5 * e);
        }
      }
    }
  }
}

// ---------------- mirror: fill strictly-lower 128-blocks from upper triangle ----------------
__global__ __launch_bounds__(256) void mirror_k(float* __restrict__ S) {
  const int Cb = blockIdx.x, Rb = blockIdx.y;
  if ((Rb >> 1) <= (Cb >> 1)) return;
  float* Sb = S + (size_t)blockIdx.z * NPTS * NPTS;
  __shared__ float t[64][65];
  const int lane = threadIdx.x & 63, w = threadIdx.x >> 6;
#pragma unroll
  for (int p = 0; p < 16; ++p) {
    const int r = w + 4 * p;
    t[r][lane] = Sb[(size_t)(Cb * 64 + r) * NPTS + Rb * 64 + lane];
  }
  __syncthreads();
#pragma unroll
  for (int p = 0; p < 16; ++p) {
    const int r = w + 4 * p;
    Sb[(size_t)(Rb * 64 + r) * NPTS + Cb * 64 + lane] = t[lane][r];
  }
}

// ---------------- monotone fp32 key ----------------
__device__ __forceinline__ unsigned mono(float f) {
  unsigned u = __float_as_uint(f);
  return (u & 0x80000000u) ? ~u : (u | 0x80000000u);
}

// ---------------- packed u64 DPP max step ----------------
#define DPP64_STEP(X, CTRL, RMASK) do {                                                   \
  unsigned lo_ = (unsigned)(X), hi_ = (unsigned)((X) >> 32);                              \
  unsigned lo2_ = (unsigned)__builtin_amdgcn_update_dpp((int)lo_, (int)lo_, CTRL, RMASK, 0xf, false); \
  unsigned hi2_ = (unsigned)__builtin_amdgcn_update_dpp((int)hi_, (int)hi_, CTRL, RMASK, 0xf, false); \
  ull o_ = ((ull)hi2_ << 32) | lo2_;                                                      \
  if (o_ > (X)) (X) = o_;                                                                 \
} while (0)

// full 64-lane argmax (slow path / start node)
__device__ __forceinline__ ull wave_amax64(ull x) {
  DPP64_STEP(x, 0x111, 0xf);
  DPP64_STEP(x, 0x112, 0xf);
  DPP64_STEP(x, 0x114, 0xf);
  DPP64_STEP(x, 0x118, 0xf);
  DPP64_STEP(x, 0x142, 0xa);
  DPP64_STEP(x, 0x143, 0xc);
  unsigned lo = (unsigned)__builtin_amdgcn_readlane((int)(unsigned)x, 63);
  unsigned hi = (unsigned)__builtin_amdgcn_readlane((int)(unsigned)(x >> 32), 63);
  return ((ull)hi << 32) | lo;
}

// ---------------- cand_k: exact top-7 + tau(=8th max) per row + fp64 rowsum ----------------
__global__ __launch_bounds__(64) void cand_k(const float* __restrict__ S,
                                             ull* __restrict__ cand8,
                                             double* __restrict__ rs) {
  const size_t r = blockIdx.x;               // ci*NPTS + row
  const int row = (int)(r & (NPTS - 1));
  const float* rowp = S + r * NPTS;
  const int lane = threadIdx.x;

  float4 q[8];
  double sum = 0.0;
#pragma unroll
  for (int c = 0; c < 8; ++c) {
    q[c] = ((const float4*)rowp)[c * 64 + lane];
    sum += (double)q[c].x; sum += (double)q[c].y; sum += (double)q[c].z; sum += (double)q[c].w;
  }
  {
    double s2 = sum;
    for (int off = 32; off > 0; off >>= 1) s2 += __shfl_down(s2, off);
    if (lane == 0) rs[r] = s2;
  }

  unsigned rem = 0;
  const int dd = row - 4 * lane;
  if (dd >= 0 && dd < 2048 && (dd & 0xFC) == 0) rem = 1u << (((dd >> 8) << 2) | (dd & 3));

  float bv; int bp;
  auto rescan = [&]() {
    bv = -INFINITY; bp = 0;
#pragma unroll
    for (int c = 0; c < 8; ++c) {
      const float xs0 = q[c].x, xs1 = q[c].y, xs2 = q[c].z, xs3 = q[c].w;
      float x0 = ((rem >> (4 * c + 0)) & 1u) ? -INFINITY : xs0;
      float x1 = ((rem >> (4 * c + 1)) & 1u) ? -INFINITY : xs1;
      float x2 = ((rem >> (4 * c + 2)) & 1u) ? -INFINITY : xs2;
      float x3 = ((rem >> (4 * c + 3)) & 1u) ? -INFINITY : xs3;
      if (x0 > bv) { bv = x0; bp = 4 * c + 0; }
      if (x1 > bv) { bv = x1; bp = 4 * c + 1; }
      if (x2 > bv) { bv = x2; bp = 4 * c + 2; }
      if (x3 > bv) { bv = x3; bp = 4 * c + 3; }
    }
  };
  rescan();

#pragma unroll 1
  for (int rnd = 0; rnd < 8; ++rnd) {
    const int gi = ((bp >> 2) << 8) + 4 * lane + (bp & 3);
    const ull pk = ((ull)mono(bv) << 32) | (unsigned)(2047 - gi);
    const ull red = wave_amax64(pk);
    if (rnd < 7) {
      if (lane == 0) cand8[r * 8 + rnd] = red;
      if (pk == red) { rem |= 1u << bp; rescan(); }
    } else {
      if (lane == 0) cand8[r * 8 + 7] = (red >> 32) << 32;
    }
  }
}

// ---------------- greedy traversal: LDS candidate table, no speculative prefetch ----------------
__global__ __launch_bounds__(64) void traverse_k(const float* __restrict__ S,
                                                 const ull* __restrict__ cand8,
                                                 const double* __restrict__ rs,
                                                 float* __restrict__ order_f, int cs) {
  extern __shared__ ull tabL[];              // [NPTS*8]
  const int ci = blockIdx.x;
  const int gb = cs + ci;
  const int lane = threadIdx.x;

  {
    float4* ls = (float4*)tabL;
    const float4* gs = (const float4*)(cand8 + (size_t)ci * NPTS * 8);
#pragma unroll 1
    for (int i0 = 0; i0 < 8192; i0 += 512) {
      float4 t[8];
#pragma unroll
      for (int j = 0; j < 8; ++j) t[j] = gs[i0 + j * 64 + lane];
#pragma unroll
      for (int j = 0; j < 8; ++j) ls[i0 + j * 64 + lane] = t[j];
    }
  }
  __syncthreads();

  // start node: argmax of fp64 rowsum (tie -> min index)
  const double* rb = rs + (size_t)ci * NPTS;
  double dv = -1.0e300; int di = 0;
#pragma unroll
  for (int c = 0; c < 32; ++c) {
    int j = c * 64 + lane;
    double v = rb[j];
    if (v > dv) { dv = v; di = j; }
  }
  for (int off = 32; off > 0; off >>= 1) {
    double vo = __shfl_down(dv, off);
    int io = __shfl_down(di, off);
    if (vo > dv || (vo == dv && io < di)) { dv = vo; di = io; }
  }
  int cur = __shfl(di, 0);

  unsigned vis = 0, visw = 0;
  if (lane == ((cur >> 2) & 63)) vis |= 1u << (((cur >> 8) << 2) | (cur & 3));
  if (lane == (cur >> 5))        visw |= 1u << (cur & 31);
  if (lane == 0) order_f[(size_t)gb * NPTS] = (float)cur;

  const float* Sb = S + (size_t)ci * NPTS * NPTS;
  const int slot = lane & 7;

#pragma unroll 1
  for (int s = 1; s < NPTS; ++s) {
    const ull e = tabL[cur * 8 + slot];                       // broadcast ds_read_b64
    const unsigned idx = 2047u - (unsigned)(e & 0xFFFFFFFFu);
    const unsigned wv = (unsigned)__shfl((int)visw, (int)(idx >> 5));
    ull mk = ((slot == 7) || ((wv >> (idx & 31)) & 1u)) ? 0ull : e;
    DPP64_STEP(mk, 0x111, 0xf);   // row_shr:1
    DPP64_STEP(mk, 0x112, 0xf);   // row_shr:2
    DPP64_STEP(mk, 0x114, 0xf);   // row_shr:4
    const unsigned kH = (unsigned)__builtin_amdgcn_readlane((int)(unsigned)(mk >> 32), 7);
    const unsigned kL = (unsigned)__builtin_amdgcn_readlane((int)(unsigned)mk, 7);
    const unsigned tH = (unsigned)__builtin_amdgcn_readlane((int)(unsigned)(e >> 32), 7);
    int nxt;
    if (kH > tH) {
      nxt = (int)(2047u - kL);
    } else {
      // slow path: load + scan the full S row (uniform branch)
      const float4* rowp = (const float4*)(Sb + (size_t)cur * NPTS);
      float4 v[8];
#pragma unroll
      for (int c = 0; c < 8; ++c) v[c] = rowp[c * 64 + lane];
      float bvv = -INFINITY; int bi = 0;
#pragma unroll
      for (int c = 0; c < 8; ++c) {
        const int base = c * 256 + 4 * lane;
        float x0 = (vis & (1u << (4 * c + 0))) ? -INFINITY : v[c].x;
        float x1 = (vis & (1u << (4 * c + 1))) ? -INFINITY : v[c].y;
        float x2 = (vis & (1u << (4 * c + 2))) ? -INFINITY : v[c].z;
        float x3 = (vis & (1u << (4 * c + 3))) ? -INFINITY : v[c].w;
        if (x0 > bvv) { bvv = x0; bi = base + 0; }
        if (x1 > bvv) { bvv = x1; bi = base + 1; }
        if (x2 > bvv) { bvv = x2; bi = base + 2; }
        if (x3 > bvv) { bvv = x3; bi = base + 3; }
      }
      const ull pk = ((ull)mono(bvv) << 32) | (unsigned)(2047 - bi);
      const ull mm = wave_amax64(pk);
      nxt = (int)(2047u - (unsigned)(mm & 0xFFFFFFFFu));
    }
    if (lane == ((nxt >> 2) & 63)) vis |= 1u << (((nxt >> 8) << 2) | (nxt & 3));
    if (lane == (nxt >> 5))        visw |= 1u << (nxt & 31);
    if (lane == 0) order_f[(size_t)gb * NPTS + s] = (float)nxt;
    cur = nxt;
  }
}

// ---------------- gather: reordered = features[order] ----------------
__global__ void gather_k(const float* __restrict__ feat, const float* __restrict__ order_f,
                         float* __restrict__ out) {
  const int bk = blockIdx.x;
  const int b = bk >> 11, k = bk & (NPTS - 1);
  const int idx = (int)order_f[(size_t)b * NPTS + k];
  const float4* src = (const float4*)(feat + ((size_t)b * NPTS + idx) * DIM);
  float4* dst = (float4*)(out + ((size_t)b * NPTS + k) * DIM);
  dst[threadIdx.x] = src[threadIdx.x];
}

extern "C" void kernel_launch(void* const* d_in, const int* in_sizes, int n_in,
                              void* d_out, int out_size, void* d_ws, size_t ws_size,
                              hipStream_t stream) {
  const float* features = (const float*)d_in[0];
  const float* coords   = (const float*)d_in[1];
  float* out = (float*)d_out;
  float* order_f = out + (size_t)BATCH * NPTS * DIM;

  static bool attr_done = false;
  if (!attr_done) {
    (void)hipFuncSetAttribute((const void*)traverse_k,
                              hipFuncAttributeMaxDynamicSharedMemorySize, 131072);
    attr_done = true;
  }

  // ws per batch: rs (N*8) + S (N*N*4) + fn (N*D*4) + cand8 (N*8*8)  -> C=16
  const size_t per_b = (size_t)NPTS * 8 + (size_t)NPTS * NPTS * 4 +
                       (size_t)NPTS * DIM * 4 + (size_t)NPTS * 8 * 8;
  int C = BATCH;
  while (C > 1 && per_b * (size_t)C > ws_size) C >>= 1;

  char* wp = (char*)d_ws;
  double* rowsum = (double*)wp;               wp += (size_t)C * NPTS * 8;
  float*  S      = (float*)wp;                wp += (size_t)C * NPTS * NPTS * 4;
  float*  fn     = (float*)wp;                wp += (size_t)C * NPTS * DIM * 4;
  ull*    cand8  = (ull*)wp;

  for (int cs = 0; cs < BATCH; cs += C) {
    normalize_k<<<dim3(C * NPTS), dim3(256), 0, stream>>>(features, fn, cs);
    gemm_k<<<dim3(16, 16, C), dim3(256), 0, stream>>>(fn, coords, S, cs);
    mirror_k<<<dim3(32, 32, C), dim3(256), 0, stream>>>(S);
    cand_k<<<dim3(C * NPTS), dim3(64), 0, stream>>>(S, cand8, rowsum);
    traverse_k<<<dim3(C), dim3(64), 131072, stream>>>(S, cand8, rowsum, order_f, cs);
  }
  gather_k<<<dim3(BATCH * NPTS), dim3(192), 0, stream>>>(features, order_f, out);
}

// Round 13
// 2011.887 us; speedup vs baseline: 1.0986x; 1.0986x over previous
//
#include <hip/hip_runtime.h>
#include <math.h>

#define BATCH 16
#define NPTS  2048
#define DIM   768
#define NCH   24      // 768 / 32 k-chunks
#define PADW  40      // bf16 row stride within a plane
#define MATSZ 15360   // 3*128*PADW ushorts per matrix per buffer
#define BUFSZ 30720   // A+B per buffer (ushorts); 2 buffers = 122880 B LDS

typedef unsigned long long ull;
typedef float f32x4 __attribute__((ext_vector_type(4)));
typedef short bf8 __attribute__((ext_vector_type(8)));          // 8 bf16 = 4 VGPR

// RNE fp32 -> bf16, bits with low 16 zeroed (== round-trip bit pattern)
__device__ __forceinline__ unsigned bfr(float x) {
  unsigned u = __float_as_uint(x);
  return (u + 0x7FFFu + ((u >> 16) & 1u)) & 0xFFFF0000u;
}
__device__ __forceinline__ unsigned short f2bf(float x) {
  unsigned u = __float_as_uint(x);
  u += 0x7FFFu + ((u >> 16) & 1u);
  return (unsigned short)(u >> 16);
}

// convert 16 fp32 -> split-3 bf16 planes and write to LDS (identical bit formula,
// packing, and layout as the verified round-9 pipeline -> S bit-identical).
__device__ __forceinline__ void cw16(const float4& x0, const float4& x1,
                                     const float4& x2, const float4& x3,
                                     unsigned short* base, int row, int half) {
  float wa[16];
  wa[0]  = x0.x; wa[1]  = x0.y; wa[2]  = x0.z; wa[3]  = x0.w;
  wa[4]  = x1.x; wa[5]  = x1.y; wa[6]  = x1.z; wa[7]  = x1.w;
  wa[8]  = x2.x; wa[9]  = x2.y; wa[10] = x2.z; wa[11] = x2.w;
  wa[12] = x3.x; wa[13] = x3.y; wa[14] = x3.z; wa[15] = x3.w;
  unsigned sa[2][3][4];
#pragma unroll
  for (int h = 0; h < 2; ++h)
#pragma unroll
    for (int j = 0; j < 8; j += 2) {
      float w0 = wa[8 * h + j], w1 = wa[8 * h + j + 1];
      unsigned a0 = bfr(w0); float r0 = w0 - __uint_as_float(a0);
      unsigned a1 = bfr(w1); float r1 = w1 - __uint_as_float(a1);
      unsigned b0 = bfr(r0); float q0 = r0 - __uint_as_float(b0);
      unsigned b1 = bfr(r1); float q1 = r1 - __uint_as_float(b1);
      unsigned c0 = bfr(q0), c1 = bfr(q1);
      sa[h][0][j >> 1] = (a0 >> 16) | (a1 & 0xFFFF0000u);
      sa[h][1][j >> 1] = (b0 >> 16) | (b1 & 0xFFFF0000u);
      sa[h][2][j >> 1] = (c0 >> 16) | (c1 & 0xFFFF0000u);
    }
#pragma unroll
  for (int pl = 0; pl < 3; ++pl)
#pragma unroll
    for (int h = 0; h < 2; ++h)
      *(uint4*)&base[pl * 5120 + row * PADW + half * 16 + 8 * h] = *(uint4*)&sa[h][pl][0];
}

// ---------------- normalize: fn = f / max(||f||,1e-12), fp64 norm (fp32 output) ----------------
__global__ void normalize_k(const float* __restrict__ feat, float* __restrict__ fn, int cs) {
  const int rn = blockIdx.x;                 // ci*NPTS + n
  const int ci = rn >> 11, n = rn & (NPTS - 1);
  const float* src = feat + ((size_t)(cs + ci) * NPTS + n) * DIM;
  const int t = threadIdx.x;                 // 256 threads
  float f0 = src[t], f1 = src[t + 256], f2 = src[t + 512];
  double s = (double)f0 * (double)f0 + (double)f1 * (double)f1 + (double)f2 * (double)f2;
  for (int off = 32; off > 0; off >>= 1) s += __shfl_down(s, off);
  __shared__ double ps[4];
  __shared__ double rbc;
  const int lane = t & 63, wid = t >> 6;
  if (lane == 0) ps[wid] = s;
  __syncthreads();
  if (t == 0) {
    double tot = ps[0] + ps[1] + ps[2] + ps[3];
    rbc = fmax(sqrt(tot), 1e-12);
  }
  __syncthreads();
  const double r = rbc;
  float* dst = fn + ((size_t)ci * NPTS + n) * DIM;
  dst[t]       = (float)((double)f0 / r);
  dst[t + 256] = (float)((double)f1 / r);
  dst[t + 512] = (float)((double)f2 / r);
}

// ---------------- similarity: S = fn.fn^T via split-3 bf16 MFMA + 0.5*exp(-d2/1e4) ------------
// Upper-triangle 128x128 tiles (bx<=by); mirror_k fills the rest.
// Round-13 structure: double-buffered bf16-split LDS (2 x 61440 B dynamic), ONE barrier
// per chunk, 2-deep named register pipeline:
//   per chunk c: issue raw loads for c+2 | convert+write c+1 -> buf(p^1) | MFMA from buf(p).
// The convert (the ~250us serial cost of round-9's barrier-sandwiched staging) is now
// independent of the MFMA stream -> compiler interleaves VALU with MFMA (separate pipes).
// Same RNE bit formula, same LDS layout per buffer, same chunk order as round 9 ->
// S bit-identical. Named reg sets (a0/b0, a1/b1) keep everything in registers (rule #20).
__global__ __launch_bounds__(256, 1) void gemm_k(const float* __restrict__ fn,
                                                 const float* __restrict__ coords,
                                                 float* __restrict__ S, int cs) {
  if (blockIdx.x > blockIdx.y) return;       // symmetry: skip strictly-lower tiles
  const int ci = blockIdx.z;
  const int i0 = blockIdx.x * 128;
  const int j0 = blockIdx.y * 128;
  const int tid  = threadIdx.x;              // 256
  const int lane = tid & 63, w = tid >> 6;
  const int wr = (w >> 1) * 64, wc = (w & 1) * 64;   // wave quadrant
  const int lo = lane & 15, quad = lane >> 4;

  extern __shared__ unsigned short sl[];     // [2 bufs][A(15360) B(15360)]

  f32x4 aH[4][4], aM[4][4], aL[4][4];
#pragma unroll
  for (int tr = 0; tr < 4; ++tr)
#pragma unroll
    for (int tc = 0; tc < 4; ++tc) {
      aH[tr][tc] = (f32x4){0.f, 0.f, 0.f, 0.f};
      aM[tr][tc] = (f32x4){0.f, 0.f, 0.f, 0.f};
      aL[tr][tc] = (f32x4){0.f, 0.f, 0.f, 0.f};
    }

  const float* fb = fn + (size_t)ci * NPTS * DIM;
  const int row  = tid >> 1;                 // staging row 0..127
  const int half = tid & 1;                  // 16-float sub-band of the k32 chunk
  const float* ag = fb + (size_t)(i0 + row) * DIM + half * 16;
  const float* bg = fb + (size_t)(j0 + row) * DIM + half * 16;

  // named raw-register sets (2-deep pipeline)
  float4 a0[4], b0[4], a1[4], b1[4];

#define LOADSET(SA, SB, KC) do {                                    \
    SA[0] = *(const float4*)(ag + (KC) + 0);                        \
    SA[1] = *(const float4*)(ag + (KC) + 4);                        \
    SA[2] = *(const float4*)(ag + (KC) + 8);                        \
    SA[3] = *(const float4*)(ag + (KC) + 12);                       \
    SB[0] = *(const float4*)(bg + (KC) + 0);                        \
    SB[1] = *(const float4*)(bg + (KC) + 4);                        \
    SB[2] = *(const float4*)(bg + (KC) + 8);                        \
    SB[3] = *(const float4*)(bg + (KC) + 12);                       \
  } while (0)

#define CWSET(SA, SB, P) do {                                       \
    cw16(SA[0], SA[1], SA[2], SA[3], sl + (P) * BUFSZ,          row, half); \
    cw16(SB[0], SB[1], SB[2], SB[3], sl + (P) * BUFSZ + MATSZ,  row, half); \
  } while (0)

#define MFMASTEP(P) do {                                            \
    const unsigned short* Ab = sl + (P) * BUFSZ;                    \
    const unsigned short* Bb = Ab + MATSZ;                          \
    bf8 A0[4], A1[4], A2[4], B0[4], B1[4], B2[4];                   \
    _Pragma("unroll")                                               \
    for (int t = 0; t < 4; ++t) {                                   \
      const int rA = wr + t * 16 + lo, rB = wc + t * 16 + lo, k8 = quad * 8; \
      A0[t] = *(const bf8*)&Ab[0 * 5120 + rA * PADW + k8];          \
      A1[t] = *(const bf8*)&Ab[1 * 5120 + rA * PADW + k8];          \
      A2[t] = *(const bf8*)&Ab[2 * 5120 + rA * PADW + k8];          \
      B0[t] = *(const bf8*)&Bb[0 * 5120 + rB * PADW + k8];          \
      B1[t] = *(const bf8*)&Bb[1 * 5120 + rB * PADW + k8];          \
      B2[t] = *(const bf8*)&Bb[2 * 5120 + rB * PADW + k8];          \
    }                                                               \
    _Pragma("unroll")                                               \
    for (int tr = 0; tr < 4; ++tr)                                  \
      _Pragma("unroll")                                             \
      for (int tc = 0; tc < 4; ++tc) {                              \
        aH[tr][tc] = __builtin_amdgcn_mfma_f32_16x16x32_bf16(A0[tr], B0[tc], aH[tr][tc], 0, 0, 0); \
        aM[tr][tc] = __builtin_amdgcn_mfma_f32_16x16x32_bf16(A0[tr], B1[tc], aM[tr][tc], 0, 0, 0); \
        aM[tr][tc] = __builtin_amdgcn_mfma_f32_16x16x32_bf16(A1[tr], B0[tc], aM[tr][tc], 0, 0, 0); \
        aL[tr][tc] = __builtin_amdgcn_mfma_f32_16x16x32_bf16(A0[tr], B2[tc], aL[tr][tc], 0, 0, 0); \
        aL[tr][tc] = __builtin_amdgcn_mfma_f32_16x16x32_bf16(A1[tr], B1[tc], aL[tr][tc], 0, 0, 0); \
        aL[tr][tc] = __builtin_amdgcn_mfma_f32_16x16x32_bf16(A2[tr], B0[tc], aL[tr][tc], 0, 0, 0); \
      }                                                             \
  } while (0)

  // prologue: chunk0 -> buf0 (convert exposed once), chunk1 raw -> set1
  LOADSET(a0, b0, 0);
  CWSET(a0, b0, 0);
  LOADSET(a1, b1, 32);
  __syncthreads();

#pragma unroll 1
  for (int cc = 0; cc < NCH; cc += 2) {
    // chunk cc (buf0): load cc+2 -> set0 | convert cc+1 -> buf1 | MFMA buf0
    if (cc + 2 < NCH) LOADSET(a0, b0, (cc + 2) * 32);
    if (cc + 1 < NCH) CWSET(a1, b1, 1);
    MFMASTEP(0);
    __syncthreads();
    // chunk cc+1 (buf1): load cc+3 -> set1 | convert cc+2 -> buf0 | MFMA buf1
    if (cc + 3 < NCH) LOADSET(a1, b1, (cc + 3) * 32);
    if (cc + 2 < NCH) CWSET(a0, b0, 0);
    MFMASTEP(1);
    __syncthreads();
  }

#undef LOADSET
#undef CWSET
#undef MFMASTEP

  // ---- probe the true C/D slot->(row,col) mapping (exact small ints in bf16/fp32) ----
  {
    const unsigned short encv = f2bf((float)lo);
    const unsigned short onev = f2bf(1.0f);
    bf8 enc, one;
#pragma unroll
    for (int t = 0; t < 8; ++t) { enc[t] = (short)encv; one[t] = (short)onev; }
    f32x4 z = (f32x4){0.f, 0.f, 0.f, 0.f};
    f32x4 d1 = __builtin_amdgcn_mfma_f32_16x16x32_bf16(enc, one, z, 0, 0, 0); // = 32*row
    f32x4 d2 = __builtin_amdgcn_mfma_f32_16x16x32_bf16(one, enc, z, 0, 0, 0); // = 32*col
    int rowp[4], colp[4];
#pragma unroll
    for (int r = 0; r < 4; ++r) {
      rowp[r] = ((int)(d1[r] * (1.0f / 32.0f))) & 15;
      colp[r] = ((int)(d2[r] * (1.0f / 32.0f))) & 15;
    }

    // epilogue: S = hi+mid+lo (fp64 sum) + 0.5*exp(-d2/1e4) (4th-order Taylor, exact regime)
    const float* cb = coords + (size_t)(cs + ci) * NPTS * 2;
    float* Sb = S + (size_t)ci * NPTS * NPTS;
#pragma unroll
    for (int r = 0; r < 4; ++r) {
      const int rl = rowp[r], cl = colp[r];
#pragma unroll
      for (int tr = 0; tr < 4; ++tr) {
        const int rowi = i0 + wr + tr * 16 + rl;
        float2 pi = *(const float2*)(cb + 2 * rowi);
        const double cix = pi.x, ciy = pi.y;
#pragma unroll
        for (int tc = 0; tc < 4; ++tc) {
          const int colj = j0 + wc + tc * 16 + cl;
          float2 pj = *(const float2*)(cb + 2 * colj);
          double dx = cix - (double)pj.x, dy = ciy - (double)pj.y;
          double x = (dx * dx + dy * dy) * (1.0 / 10000.0);
          double e = 1.0 - x * (1.0 - x * (0.5 - x * ((1.0 / 6.0) - x * (1.0 / 24.0))));
          double sem = (double)aH[tr][tc][r] + (double)aM[tr][tc][r] + (double)aL[tr][tc][r];
          Sb[(size_t)rowi * NPTS + colj] = (float)(sem + 0.5 * e);
        }
      }
    }
  }
}

// ---------------- mirror: fill strictly-lower 128-blocks from upper triangle ----------------
__global__ __launch_bounds__(256) void mirror_k(float* __restrict__ S) {
  const int Cb = blockIdx.x, Rb = blockIdx.y;
  if ((Rb >> 1) <= (Cb >> 1)) return;
  float* Sb = S + (size_t)blockIdx.z * NPTS * NPTS;
  __shared__ float t[64][65];
  const int lane = threadIdx.x & 63, w = threadIdx.x >> 6;
#pragma unroll
  for (int p = 0; p < 16; ++p) {
    const int r = w + 4 * p;
    t[r][lane] = Sb[(size_t)(Cb * 64 + r) * NPTS + Rb * 64 + lane];
  }
  __syncthreads();
#pragma unroll
  for (int p = 0; p < 16; ++p) {
    const int r = w + 4 * p;
    Sb[(size_t)(Rb * 64 + r) * NPTS + Cb * 64 + lane] = t[lane][r];
  }
}

// ---------------- monotone fp32 key ----------------
__device__ __forceinline__ unsigned mono(float f) {
  unsigned u = __float_as_uint(f);
  return (u & 0x80000000u) ? ~u : (u | 0x80000000u);
}

// ---------------- packed u64 DPP max step ----------------
#define DPP64_STEP(X, CTRL, RMASK) do {                                                   \
  unsigned lo_ = (unsigned)(X), hi_ = (unsigned)((X) >> 32);                              \
  unsigned lo2_ = (unsigned)__builtin_amdgcn_update_dpp((int)lo_, (int)lo_, CTRL, RMASK, 0xf, false); \
  unsigned hi2_ = (unsigned)__builtin_amdgcn_update_dpp((int)hi_, (int)hi_, CTRL, RMASK, 0xf, false); \
  ull o_ = ((ull)hi2_ << 32) | lo2_;                                                      \
  if (o_ > (X)) (X) = o_;                                                                 \
} while (0)

// full 64-lane argmax (slow path / start node)
__device__ __forceinline__ ull wave_amax64(ull x) {
  DPP64_STEP(x, 0x111, 0xf);
  DPP64_STEP(x, 0x112, 0xf);
  DPP64_STEP(x, 0x114, 0xf);
  DPP64_STEP(x, 0x118, 0xf);
  DPP64_STEP(x, 0x142, 0xa);
  DPP64_STEP(x, 0x143, 0xc);
  unsigned lo = (unsigned)__builtin_amdgcn_readlane((int)(unsigned)x, 63);
  unsigned hi = (unsigned)__builtin_amdgcn_readlane((int)(unsigned)(x >> 32), 63);
  return ((ull)hi << 32) | lo;
}

// ---------------- cand_k: exact top-7 + tau(=8th max) per row + fp64 rowsum ----------------
__global__ __launch_bounds__(64) void cand_k(const float* __restrict__ S,
                                             ull* __restrict__ cand8,
                                             double* __restrict__ rs) {
  const size_t r = blockIdx.x;               // ci*NPTS + row
  const int row = (int)(r & (NPTS - 1));
  const float* rowp = S + r * NPTS;
  const int lane = threadIdx.x;

  float4 q[8];
  double sum = 0.0;
#pragma unroll
  for (int c = 0; c < 8; ++c) {
    q[c] = ((const float4*)rowp)[c * 64 + lane];
    sum += (double)q[c].x; sum += (double)q[c].y; sum += (double)q[c].z; sum += (double)q[c].w;
  }
  {
    double s2 = sum;
    for (int off = 32; off > 0; off >>= 1) s2 += __shfl_down(s2, off);
    if (lane == 0) rs[r] = s2;
  }

  unsigned rem = 0;
  const int dd = row - 4 * lane;
  if (dd >= 0 && dd < 2048 && (dd & 0xFC) == 0) rem = 1u << (((dd >> 8) << 2) | (dd & 3));

  float bv; int bp;
  auto rescan = [&]() {
    bv = -INFINITY; bp = 0;
#pragma unroll
    for (int c = 0; c < 8; ++c) {
      const float xs0 = q[c].x, xs1 = q[c].y, xs2 = q[c].z, xs3 = q[c].w;
      float x0 = ((rem >> (4 * c + 0)) & 1u) ? -INFINITY : xs0;
      float x1 = ((rem >> (4 * c + 1)) & 1u) ? -INFINITY : xs1;
      float x2 = ((rem >> (4 * c + 2)) & 1u) ? -INFINITY : xs2;
      float x3 = ((rem >> (4 * c + 3)) & 1u) ? -INFINITY : xs3;
      if (x0 > bv) { bv = x0; bp = 4 * c + 0; }
      if (x1 > bv) { bv = x1; bp = 4 * c + 1; }
      if (x2 > bv) { bv = x2; bp = 4 * c + 2; }
      if (x3 > bv) { bv = x3; bp = 4 * c + 3; }
    }
  };
  rescan();

#pragma unroll 1
  for (int rnd = 0; rnd < 8; ++rnd) {
    const int gi = ((bp >> 2) << 8) + 4 * lane + (bp & 3);
    const ull pk = ((ull)mono(bv) << 32) | (unsigned)(2047 - gi);
    const ull red = wave_amax64(pk);
    if (rnd < 7) {
      if (lane == 0) cand8[r * 8 + rnd] = red;
      if (pk == red) { rem |= 1u << bp; rescan(); }
    } else {
      if (lane == 0) cand8[r * 8 + 7] = (red >> 32) << 32;
    }
  }
}

// ---------------- greedy traversal: LDS candidate table, no speculative prefetch ----------------
__global__ __launch_bounds__(64) void traverse_k(const float* __restrict__ S,
                                                 const ull* __restrict__ cand8,
                                                 const double* __restrict__ rs,
                                                 float* __restrict__ order_f, int cs) {
  extern __shared__ ull tabL[];              // [NPTS*8]
  const int ci = blockIdx.x;
  const int gb = cs + ci;
  const int lane = threadIdx.x;

  {
    float4* ls = (float4*)tabL;
    const float4* gs = (const float4*)(cand8 + (size_t)ci * NPTS * 8);
#pragma unroll 1
    for (int i0 = 0; i0 < 8192; i0 += 512) {
      float4 t[8];
#pragma unroll
      for (int j = 0; j < 8; ++j) t[j] = gs[i0 + j * 64 + lane];
#pragma unroll
      for (int j = 0; j < 8; ++j) ls[i0 + j * 64 + lane] = t[j];
    }
  }
  __syncthreads();

  // start node: argmax of fp64 rowsum (tie -> min index)
  const double* rb = rs + (size_t)ci * NPTS;
  double dv = -1.0e300; int di = 0;
#pragma unroll
  for (int c = 0; c < 32; ++c) {
    int j = c * 64 + lane;
    double v = rb[j];
    if (v > dv) { dv = v; di = j; }
  }
  for (int off = 32; off > 0; off >>= 1) {
    double vo = __shfl_down(dv, off);
    int io = __shfl_down(di, off);
    if (vo > dv || (vo == dv && io < di)) { dv = vo; di = io; }
  }
  int cur = __shfl(di, 0);

  unsigned vis = 0, visw = 0;
  if (lane == ((cur >> 2) & 63)) vis |= 1u << (((cur >> 8) << 2) | (cur & 3));
  if (lane == (cur >> 5))        visw |= 1u << (cur & 31);
  if (lane == 0) order_f[(size_t)gb * NPTS] = (float)cur;

  const float* Sb = S + (size_t)ci * NPTS * NPTS;
  const int slot = lane & 7;

#pragma unroll 1
  for (int s = 1; s < NPTS; ++s) {
    const ull e = tabL[cur * 8 + slot];                       // broadcast ds_read_b64
    const unsigned idx = 2047u - (unsigned)(e & 0xFFFFFFFFu);
    const unsigned wv = (unsigned)__shfl((int)visw, (int)(idx >> 5));
    ull mk = ((slot == 7) || ((wv >> (idx & 31)) & 1u)) ? 0ull : e;
    DPP64_STEP(mk, 0x111, 0xf);   // row_shr:1
    DPP64_STEP(mk, 0x112, 0xf);   // row_shr:2
    DPP64_STEP(mk, 0x114, 0xf);   // row_shr:4
    const unsigned kH = (unsigned)__builtin_amdgcn_readlane((int)(unsigned)(mk >> 32), 7);
    const unsigned kL = (unsigned)__builtin_amdgcn_readlane((int)(unsigned)mk, 7);
    const unsigned tH = (unsigned)__builtin_amdgcn_readlane((int)(unsigned)(e >> 32), 7);
    int nxt;
    if (kH > tH) {
      nxt = (int)(2047u - kL);
    } else {
      // slow path: load + scan the full S row (uniform branch)
      const float4* rowp = (const float4*)(Sb + (size_t)cur * NPTS);
      float4 v[8];
#pragma unroll
      for (int c = 0; c < 8; ++c) v[c] = rowp[c * 64 + lane];
      float bvv = -INFINITY; int bi = 0;
#pragma unroll
      for (int c = 0; c < 8; ++c) {
        const int base = c * 256 + 4 * lane;
        float x0 = (vis & (1u << (4 * c + 0))) ? -INFINITY : v[c].x;
        float x1 = (vis & (1u << (4 * c + 1))) ? -INFINITY : v[c].y;
        float x2 = (vis & (1u << (4 * c + 2))) ? -INFINITY : v[c].z;
        float x3 = (vis & (1u << (4 * c + 3))) ? -INFINITY : v[c].w;
        if (x0 > bvv) { bvv = x0; bi = base + 0; }
        if (x1 > bvv) { bvv = x1; bi = base + 1; }
        if (x2 > bvv) { bvv = x2; bi = base + 2; }
        if (x3 > bvv) { bvv = x3; bi = base + 3; }
      }
      const ull pk = ((ull)mono(bvv) << 32) | (unsigned)(2047 - bi);
      const ull mm = wave_amax64(pk);
      nxt = (int)(2047u - (unsigned)(mm & 0xFFFFFFFFu));
    }
    if (lane == ((nxt >> 2) & 63)) vis |= 1u << (((nxt >> 8) << 2) | (nxt & 3));
    if (lane == (nxt >> 5))        visw |= 1u << (nxt & 31);
    if (lane == 0) order_f[(size_t)gb * NPTS + s] = (float)nxt;
    cur = nxt;
  }
}

// ---------------- gather: reordered = features[order] ----------------
__global__ void gather_k(const float* __restrict__ feat, const float* __restrict__ order_f,
                         float* __restrict__ out) {
  const int bk = blockIdx.x;
  const int b = bk >> 11, k = bk & (NPTS - 1);
  const int idx = (int)order_f[(size_t)b * NPTS + k];
  const float4* src = (const float4*)(feat + ((size_t)b * NPTS + idx) * DIM);
  float4* dst = (float4*)(out + ((size_t)b * NPTS + k) * DIM);
  dst[threadIdx.x] = src[threadIdx.x];
}

extern "C" void kernel_launch(void* const* d_in, const int* in_sizes, int n_in,
                              void* d_out, int out_size, void* d_ws, size_t ws_size,
                              hipStream_t stream) {
  const float* features = (const float*)d_in[0];
  const float* coords   = (const float*)d_in[1];
  float* out = (float*)d_out;
  float* order_f = out + (size_t)BATCH * NPTS * DIM;

  const int gemm_lds = 2 * BUFSZ * 2;        // 122880 B

  static bool attr_done = false;
  if (!attr_done) {
    (void)hipFuncSetAttribute((const void*)traverse_k,
                              hipFuncAttributeMaxDynamicSharedMemorySize, 131072);
    (void)hipFuncSetAttribute((const void*)gemm_k,
                              hipFuncAttributeMaxDynamicSharedMemorySize, gemm_lds);
    attr_done = true;
  }

  // ws per batch: rs (N*8) + S (N*N*4) + fn (N*D*4) + cand8 (N*8*8)  -> C=16
  const size_t per_b = (size_t)NPTS * 8 + (size_t)NPTS * NPTS * 4 +
                       (size_t)NPTS * DIM * 4 + (size_t)NPTS * 8 * 8;
  int C = BATCH;
  while (C > 1 && per_b * (size_t)C > ws_size) C >>= 1;

  char* wp = (char*)d_ws;
  double* rowsum = (double*)wp;               wp += (size_t)C * NPTS * 8;
  float*  S      = (float*)wp;                wp += (size_t)C * NPTS * NPTS * 4;
  float*  fn     = (float*)wp;                wp += (size_t)C * NPTS * DIM * 4;
  ull*    cand8  = (ull*)wp;

  for (int cs = 0; cs < BATCH; cs += C) {
    normalize_k<<<dim3(C * NPTS), dim3(256), 0, stream>>>(features, fn, cs);
    gemm_k<<<dim3(16, 16, C), dim3(256), gemm_lds, stream>>>(fn, coords, S, cs);
    mirror_k<<<dim3(32, 32, C), dim3(256), 0, stream>>>(S);
    cand_k<<<dim3(C * NPTS), dim3(64), 0, stream>>>(S, cand8, rowsum);
    traverse_k<<<dim3(C), dim3(64), 131072, stream>>>(S, cand8, rowsum, order_f, cs);
  }
  gather_k<<<dim3(BATCH * NPTS), dim3(192), 0, stream>>>(features, order_f, out);
}

// Round 15
// 1781.423 us; speedup vs baseline: 1.2407x; 1.1294x over previous
//
#include <hip/hip_runtime.h>
#include <math.h>

#define BATCH 16
#define NPTS  2048
#define DIM   768
#define NCH   24      // 768 / 32 k-chunks
#define PADW  40      // bf16 row stride within a plane

typedef unsigned long long ull;
typedef float f32x4 __attribute__((ext_vector_type(4)));
typedef short bf8 __attribute__((ext_vector_type(8)));          // 8 bf16 = 4 VGPR

// RNE fp32 -> bf16, bits with low 16 zeroed (== round-trip bit pattern)
__device__ __forceinline__ unsigned bfr(float x) {
  unsigned u = __float_as_uint(x);
  return (u + 0x7FFFu + ((u >> 16) & 1u)) & 0xFFFF0000u;
}
__device__ __forceinline__ unsigned short f2bf(float x) {
  unsigned u = __float_as_uint(x);
  u += 0x7FFFu + ((u >> 16) & 1u);
  return (unsigned short)(u >> 16);
}

// ---------------- normalize: fn = f / max(||f||,1e-12), fp64 norm (fp32 output) ----------------
__global__ void normalize_k(const float* __restrict__ feat, float* __restrict__ fn, int cs) {
  const int rn = blockIdx.x;                 // ci*NPTS + n
  const int ci = rn >> 11, n = rn & (NPTS - 1);
  const float* src = feat + ((size_t)(cs + ci) * NPTS + n) * DIM;
  const int t = threadIdx.x;                 // 256 threads
  float f0 = src[t], f1 = src[t + 256], f2 = src[t + 512];
  double s = (double)f0 * (double)f0 + (double)f1 * (double)f1 + (double)f2 * (double)f2;
  for (int off = 32; off > 0; off >>= 1) s += __shfl_down(s, off);
  __shared__ double ps[4];
  __shared__ double rbc;
  const int lane = t & 63, wid = t >> 6;
  if (lane == 0) ps[wid] = s;
  __syncthreads();
  if (t == 0) {
    double tot = ps[0] + ps[1] + ps[2] + ps[3];
    rbc = fmax(sqrt(tot), 1e-12);
  }
  __syncthreads();
  const double r = rbc;
  float* dst = fn + ((size_t)ci * NPTS + n) * DIM;
  dst[t]       = (float)((double)f0 / r);
  dst[t + 256] = (float)((double)f1 / r);
  dst[t + 512] = (float)((double)f2 / r);
}

// ---------------- similarity: S = fn.fn^T via split-3 bf16 MFMA + 0.5*exp(-d2/1e4) ------------
// Upper-triangle 128x128 tiles (bx<=by); mirror_k fills the rest.
// Round-14/15: 512 threads / 8 waves per block, each wave owns a 64x32 sub-tile (4x2 MFMA
// tiles). Rounds 9-13 showed the 4-wave lockstep block leaves ~50% of cycles as unhidden
// latency (1 wave/SIMD); 8 waves gives 2 waves/SIMD so one wave's MFMA stream hides the
// other's ds_read/barrier latency (m114), and per-wave serial work halves (48 MFMA +
// 18 ds_read per chunk). LDS layout, split formula, and per-tile accumulation order are
// IDENTICAL to the verified round-9 kernel -> S bit-identical.
__global__ __launch_bounds__(512, 1) void gemm_k(const float* __restrict__ fn,
                                                 const float* __restrict__ coords,
                                                 float* __restrict__ S, int cs) {
  if (blockIdx.x > blockIdx.y) return;       // symmetry: skip strictly-lower tiles
  const int ci = blockIdx.z;
  const int i0 = blockIdx.x * 128;
  const int j0 = blockIdx.y * 128;
  const int tid  = threadIdx.x;              // 512
  const int lane = tid & 63, w = tid >> 6;   // 8 waves
  const int wrow = (w >> 2) * 64, wcol = (w & 3) * 32;   // wave sub-tile origin
  const int lo = lane & 15, quad = lane >> 4;

  __shared__ unsigned short At[3][128][PADW]; // 30720 B
  __shared__ unsigned short Bt[3][128][PADW]; // 30720 B

  f32x4 aH[4][2], aM[4][2], aL[4][2];
#pragma unroll
  for (int tr = 0; tr < 4; ++tr)
#pragma unroll
    for (int tc = 0; tc < 2; ++tc) {
      aH[tr][tc] = (f32x4){0.f, 0.f, 0.f, 0.f};
      aM[tr][tc] = (f32x4){0.f, 0.f, 0.f, 0.f};
      aL[tr][tc] = (f32x4){0.f, 0.f, 0.f, 0.f};
    }

  const float* fb = fn + (size_t)ci * NPTS * DIM;
  const int row = tid >> 2;                  // staging row 0..127 (4 threads/row)
  const int q   = tid & 3;                   // 8-float sub-band of the k32 chunk
  const float* ag = fb + (size_t)(i0 + row) * DIM + q * 8;
  const float* bg = fb + (size_t)(j0 + row) * DIM + q * 8;

  float4 fa0, fa1, fb0, fb1;
  // prefetch chunk 0
  fa0 = *(const float4*)(ag);     fa1 = *(const float4*)(ag + 4);
  fb0 = *(const float4*)(bg);     fb1 = *(const float4*)(bg + 4);

#pragma unroll 1
  for (int c = 0; c < NCH; ++c) {
    __syncthreads();               // previous chunk's readers done
    // ---- convert 8 elems/matrix -> split-3 planes, write (same formula/layout as r9) ----
    {
      float wa[8] = { fa0.x, fa0.y, fa0.z, fa0.w, fa1.x, fa1.y, fa1.z, fa1.w };
      float wb[8] = { fb0.x, fb0.y, fb0.z, fb0.w, fb1.x, fb1.y, fb1.z, fb1.w };
      unsigned sa[3][4], sb[3][4];
#pragma unroll
      for (int j = 0; j < 8; j += 2) {
        {
          float w0 = wa[j], w1 = wa[j + 1];
          unsigned a0 = bfr(w0); float r0 = w0 - __uint_as_float(a0);
          unsigned a1 = bfr(w1); float r1 = w1 - __uint_as_float(a1);
          unsigned b0 = bfr(r0); float q0 = r0 - __uint_as_float(b0);
          unsigned b1 = bfr(r1); float q1 = r1 - __uint_as_float(b1);
          sa[0][j >> 1] = (a0 >> 16) | (a1 & 0xFFFF0000u);
          sa[1][j >> 1] = (b0 >> 16) | (b1 & 0xFFFF0000u);
          sa[2][j >> 1] = (bfr(q0) >> 16) | (bfr(q1) & 0xFFFF0000u);
        }
        {
          float w0 = wb[j], w1 = wb[j + 1];
          unsigned a0 = bfr(w0); float r0 = w0 - __uint_as_float(a0);
          unsigned a1 = bfr(w1); float r1 = w1 - __uint_as_float(a1);
          unsigned b0 = bfr(r0); float q0 = r0 - __uint_as_float(b0);
          unsigned b1 = bfr(r1); float q1 = r1 - __uint_as_float(b1);
          sb[0][j >> 1] = (a0 >> 16) | (a1 & 0xFFFF0000u);
          sb[1][j >> 1] = (b0 >> 16) | (b1 & 0xFFFF0000u);
          sb[2][j >> 1] = (bfr(q0) >> 16) | (bfr(q1) & 0xFFFF0000u);
        }
      }
#pragma unroll
      for (int pl = 0; pl < 3; ++pl) {
        *(uint4*)&At[pl][row][q * 8] = *(uint4*)&sa[pl][0];
        *(uint4*)&Bt[pl][row][q * 8] = *(uint4*)&sb[pl][0];
      }
    }
    __syncthreads();
    if (c + 1 < NCH) {             // prefetch next chunk; overlaps MFMA below
      const int kc = (c + 1) * 32;
      fa0 = *(const float4*)(ag + kc);  fa1 = *(const float4*)(ag + kc + 4);
      fb0 = *(const float4*)(bg + kc);  fb1 = *(const float4*)(bg + kc + 4);
    }
    bf8 A0[4], A1[4], A2[4], B0[2], B1[2], B2[2];
#pragma unroll
    for (int t = 0; t < 4; ++t) {
      const int rA = wrow + t * 16 + lo, k8 = quad * 8;
      A0[t] = *(const bf8*)&At[0][rA][k8];
      A1[t] = *(const bf8*)&At[1][rA][k8];
      A2[t] = *(const bf8*)&At[2][rA][k8];
    }
#pragma unroll
    for (int t = 0; t < 2; ++t) {
      const int rB = wcol + t * 16 + lo, k8 = quad * 8;
      B0[t] = *(const bf8*)&Bt[0][rB][k8];
      B1[t] = *(const bf8*)&Bt[1][rB][k8];
      B2[t] = *(const bf8*)&Bt[2][rB][k8];
    }
#pragma unroll
    for (int tr = 0; tr < 4; ++tr)
#pragma unroll
      for (int tc = 0; tc < 2; ++tc) {
        aH[tr][tc] = __builtin_amdgcn_mfma_f32_16x16x32_bf16(A0[tr], B0[tc], aH[tr][tc], 0, 0, 0);
        aM[tr][tc] = __builtin_amdgcn_mfma_f32_16x16x32_bf16(A0[tr], B1[tc], aM[tr][tc], 0, 0, 0);
        aM[tr][tc] = __builtin_amdgcn_mfma_f32_16x16x32_bf16(A1[tr], B0[tc], aM[tr][tc], 0, 0, 0);
        aL[tr][tc] = __builtin_amdgcn_mfma_f32_16x16x32_bf16(A0[tr], B2[tc], aL[tr][tc], 0, 0, 0);
        aL[tr][tc] = __builtin_amdgcn_mfma_f32_16x16x32_bf16(A1[tr], B1[tc], aL[tr][tc], 0, 0, 0);
        aL[tr][tc] = __builtin_amdgcn_mfma_f32_16x16x32_bf16(A2[tr], B0[tc], aL[tr][tc], 0, 0, 0);
      }
  }

  // ---- probe the true C/D slot->(row,col) mapping (exact small ints in bf16/fp32) ----
  {
    const unsigned short encv = f2bf((float)lo);
    const unsigned short onev = f2bf(1.0f);
    bf8 enc, one;
#pragma unroll
    for (int t = 0; t < 8; ++t) { enc[t] = (short)encv; one[t] = (short)onev; }
    f32x4 z = (f32x4){0.f, 0.f, 0.f, 0.f};
    f32x4 d1 = __builtin_amdgcn_mfma_f32_16x16x32_bf16(enc, one, z, 0, 0, 0); // = 32*row
    f32x4 d2 = __builtin_amdgcn_mfma_f32_16x16x32_bf16(one, enc, z, 0, 0, 0); // = 32*col
    int rowp[4], colp[4];
#pragma unroll
    for (int r = 0; r < 4; ++r) {
      rowp[r] = ((int)(d1[r] * (1.0f / 32.0f))) & 15;
      colp[r] = ((int)(d2[r] * (1.0f / 32.0f))) & 15;
    }

    // epilogue: S = hi+mid+lo (fp64 sum) + 0.5*exp(-d2/1e4) (4th-order Taylor, exact regime)
    const float* cb = coords + (size_t)(cs + ci) * NPTS * 2;
    float* Sb = S + (size_t)ci * NPTS * NPTS;
#pragma unroll
    for (int r = 0; r < 4; ++r) {
      const int rl = rowp[r], cl = colp[r];
#pragma unroll
      for (int tr = 0; tr < 4; ++tr) {
        const int rowi = i0 + wrow + tr * 16 + rl;
        float2 pi = *(const float2*)(cb + 2 * rowi);
        const double cix = pi.x, ciy = pi.y;
#pragma unroll
        for (int tc = 0; tc < 2; ++tc) {
          const int colj = j0 + wcol + tc * 16 + cl;
          float2 pj = *(const float2*)(cb + 2 * colj);
          double dx = cix - (double)pj.x, dy = ciy - (double)pj.y;
          double x = (dx * dx + dy * dy) * (1.0 / 10000.0);
          double e = 1.0 - x * (1.0 - x * (0.5 - x * ((1.0 / 6.0) - x * (1.0 / 24.0))));
          double sem = (double)aH[tr][tc][r] + (double)aM[tr][tc][r] + (double)aL[tr][tc][r];
          Sb[(size_t)rowi * NPTS + colj] = (float)(sem + 0.5 * e);
        }
      }
    }
  }
}

// ---------------- mirror: fill strictly-lower 128-blocks from upper triangle ----------------
__global__ __launch_bounds__(256) void mirror_k(float* __restrict__ S) {
  const int Cb = blockIdx.x, Rb = blockIdx.y;
  if ((Rb >> 1) <= (Cb >> 1)) return;
  float* Sb = S + (size_t)blockIdx.z * NPTS * NPTS;
  __shared__ float t[64][65];
  const int lane = threadIdx.x & 63, w = threadIdx.x >> 6;
#pragma unroll
  for (int p = 0; p < 16; ++p) {
    const int r = w + 4 * p;
    t[r][lane] = Sb[(size_t)(Cb * 64 + r) * NPTS + Rb * 64 + lane];
  }
  __syncthreads();
#pragma unroll
  for (int p = 0; p < 16; ++p) {
    const int r = w + 4 * p;
    Sb[(size_t)(Rb * 64 + r) * NPTS + Cb * 64 + lane] = t[lane][r];
  }
}

// ---------------- monotone fp32 key ----------------
__device__ __forceinline__ unsigned mono(float f) {
  unsigned u = __float_as_uint(f);
  return (u & 0x80000000u) ? ~u : (u | 0x80000000u);
}

// ---------------- packed u64 DPP max step ----------------
#define DPP64_STEP(X, CTRL, RMASK) do {                                                   \
  unsigned lo_ = (unsigned)(X), hi_ = (unsigned)((X) >> 32);                              \
  unsigned lo2_ = (unsigned)__builtin_amdgcn_update_dpp((int)lo_, (int)lo_, CTRL, RMASK, 0xf, false); \
  unsigned hi2_ = (unsigned)__builtin_amdgcn_update_dpp((int)hi_, (int)hi_, CTRL, RMASK, 0xf, false); \
  ull o_ = ((ull)hi2_ << 32) | lo2_;                                                      \
  if (o_ > (X)) (X) = o_;                                                                 \
} while (0)

// full 64-lane argmax (slow path / start node)
__device__ __forceinline__ ull wave_amax64(ull x) {
  DPP64_STEP(x, 0x111, 0xf);
  DPP64_STEP(x, 0x112, 0xf);
  DPP64_STEP(x, 0x114, 0xf);
  DPP64_STEP(x, 0x118, 0xf);
  DPP64_STEP(x, 0x142, 0xa);
  DPP64_STEP(x, 0x143, 0xc);
  unsigned lo = (unsigned)__builtin_amdgcn_readlane((int)(unsigned)x, 63);
  unsigned hi = (unsigned)__builtin_amdgcn_readlane((int)(unsigned)(x >> 32), 63);
  return ((ull)hi << 32) | lo;
}

// ---------------- cand_k: exact top-7 + tau(=8th max) per row + fp64 rowsum ----------------
__global__ __launch_bounds__(64) void cand_k(const float* __restrict__ S,
                                             ull* __restrict__ cand8,
                                             double* __restrict__ rs) {
  const size_t r = blockIdx.x;               // ci*NPTS + row
  const int row = (int)(r & (NPTS - 1));
  const float* rowp = S + r * NPTS;
  const int lane = threadIdx.x;

  float4 q[8];
  double sum = 0.0;
#pragma unroll
  for (int c = 0; c < 8; ++c) {
    q[c] = ((const float4*)rowp)[c * 64 + lane];
    sum += (double)q[c].x; sum += (double)q[c].y; sum += (double)q[c].z; sum += (double)q[c].w;
  }
  {
    double s2 = sum;
    for (int off = 32; off > 0; off >>= 1) s2 += __shfl_down(s2, off);
    if (lane == 0) rs[r] = s2;
  }

  unsigned rem = 0;
  const int dd = row - 4 * lane;
  if (dd >= 0 && dd < 2048 && (dd & 0xFC) == 0) rem = 1u << (((dd >> 8) << 2) | (dd & 3));

  float bv; int bp;
  auto rescan = [&]() {
    bv = -INFINITY; bp = 0;
#pragma unroll
    for (int c = 0; c < 8; ++c) {
      const float xs0 = q[c].x, xs1 = q[c].y, xs2 = q[c].z, xs3 = q[c].w;
      float x0 = ((rem >> (4 * c + 0)) & 1u) ? -INFINITY : xs0;
      float x1 = ((rem >> (4 * c + 1)) & 1u) ? -INFINITY : xs1;
      float x2 = ((rem >> (4 * c + 2)) & 1u) ? -INFINITY : xs2;
      float x3 = ((rem >> (4 * c + 3)) & 1u) ? -INFINITY : xs3;
      if (x0 > bv) { bv = x0; bp = 4 * c + 0; }
      if (x1 > bv) { bv = x1; bp = 4 * c + 1; }
      if (x2 > bv) { bv = x2; bp = 4 * c + 2; }
      if (x3 > bv) { bv = x3; bp = 4 * c + 3; }
    }
  };
  rescan();

#pragma unroll 1
  for (int rnd = 0; rnd < 8; ++rnd) {
    const int gi = ((bp >> 2) << 8) + 4 * lane + (bp & 3);
    const ull pk = ((ull)mono(bv) << 32) | (unsigned)(2047 - gi);
    const ull red = wave_amax64(pk);
    if (rnd < 7) {
      if (lane == 0) cand8[r * 8 + rnd] = red;
      if (pk == red) { rem |= 1u << bp; rescan(); }
    } else {
      if (lane == 0) cand8[r * 8 + 7] = (red >> 32) << 32;
    }
  }
}

// ---------------- greedy traversal: LDS candidate table, no speculative prefetch ----------------
__global__ __launch_bounds__(64) void traverse_k(const float* __restrict__ S,
                                                 const ull* __restrict__ cand8,
                                                 const double* __restrict__ rs,
                                                 float* __restrict__ order_f, int cs) {
  extern __shared__ ull tabL[];              // [NPTS*8]
  const int ci = blockIdx.x;
  const int gb = cs + ci;
  const int lane = threadIdx.x;

  {
    float4* ls = (float4*)tabL;
    const float4* gs = (const float4*)(cand8 + (size_t)ci * NPTS * 8);
#pragma unroll 1
    for (int i0 = 0; i0 < 8192; i0 += 512) {
      float4 t[8];
#pragma unroll
      for (int j = 0; j < 8; ++j) t[j] = gs[i0 + j * 64 + lane];
#pragma unroll
      for (int j = 0; j < 8; ++j) ls[i0 + j * 64 + lane] = t[j];
    }
  }
  __syncthreads();

  // start node: argmax of fp64 rowsum (tie -> min index)
  const double* rb = rs + (size_t)ci * NPTS;
  double dv = -1.0e300; int di = 0;
#pragma unroll
  for (int c = 0; c < 32; ++c) {
    int j = c * 64 + lane;
    double v = rb[j];
    if (v > dv) { dv = v; di = j; }
  }
  for (int off = 32; off > 0; off >>= 1) {
    double vo = __shfl_down(dv, off);
    int io = __shfl_down(di, off);
    if (vo > dv || (vo == dv && io < di)) { dv = vo; di = io; }
  }
  int cur = __shfl(di, 0);

  unsigned vis = 0, visw = 0;
  if (lane == ((cur >> 2) & 63)) vis |= 1u << (((cur >> 8) << 2) | (cur & 3));
  if (lane == (cur >> 5))        visw |= 1u << (cur & 31);
  if (lane == 0) order_f[(size_t)gb * NPTS] = (float)cur;

  const float* Sb = S + (size_t)ci * NPTS * NPTS;
  const int slot = lane & 7;

#pragma unroll 1
  for (int s = 1; s < NPTS; ++s) {
    const ull e = tabL[cur * 8 + slot];                       // broadcast ds_read_b64
    const unsigned idx = 2047u - (unsigned)(e & 0xFFFFFFFFu);
    const unsigned wv = (unsigned)__shfl((int)visw, (int)(idx >> 5));
    ull mk = ((slot == 7) || ((wv >> (idx & 31)) & 1u)) ? 0ull : e;
    DPP64_STEP(mk, 0x111, 0xf);   // row_shr:1
    DPP64_STEP(mk, 0x112, 0xf);   // row_shr:2
    DPP64_STEP(mk, 0x114, 0xf);   // row_shr:4
    const unsigned kH = (unsigned)__builtin_amdgcn_readlane((int)(unsigned)(mk >> 32), 7);
    const unsigned kL = (unsigned)__builtin_amdgcn_readlane((int)(unsigned)mk, 7);
    const unsigned tH = (unsigned)__builtin_amdgcn_readlane((int)(unsigned)(e >> 32), 7);
    int nxt;
    if (kH > tH) {
      nxt = (int)(2047u - kL);
    } else {
      // slow path: load + scan the full S row (uniform branch)
      const float4* rowp = (const float4*)(Sb + (size_t)cur * NPTS);
      float4 v[8];
#pragma unroll
      for (int c = 0; c < 8; ++c) v[c] = rowp[c * 64 + lane];
      float bvv = -INFINITY; int bi = 0;
#pragma unroll
      for (int c = 0; c < 8; ++c) {
        const int base = c * 256 + 4 * lane;
        float x0 = (vis & (1u << (4 * c + 0))) ? -INFINITY : v[c].x;
        float x1 = (vis & (1u << (4 * c + 1))) ? -INFINITY : v[c].y;
        float x2 = (vis & (1u << (4 * c + 2))) ? -INFINITY : v[c].z;
        float x3 = (vis & (1u << (4 * c + 3))) ? -INFINITY : v[c].w;
        if (x0 > bvv) { bvv = x0; bi = base + 0; }
        if (x1 > bvv) { bvv = x1; bi = base + 1; }
        if (x2 > bvv) { bvv = x2; bi = base + 2; }
        if (x3 > bvv) { bvv = x3; bi = base + 3; }
      }
      const ull pk = ((ull)mono(bvv) << 32) | (unsigned)(2047 - bi);
      const ull mm = wave_amax64(pk);
      nxt = (int)(2047u - (unsigned)(mm & 0xFFFFFFFFu));
    }
    if (lane == ((nxt >> 2) & 63)) vis |= 1u << (((nxt >> 8) << 2) | (nxt & 3));
    if (lane == (nxt >> 5))        visw |= 1u << (nxt & 31);
    if (lane == 0) order_f[(size_t)gb * NPTS + s] = (float)nxt;
    cur = nxt;
  }
}

// ---------------- gather: reordered = features[order] ----------------
__global__ void gather_k(const float* __restrict__ feat, const float* __restrict__ order_f,
                         float* __restrict__ out) {
  const int bk = blockIdx.x;
  const int b = bk >> 11, k = bk & (NPTS - 1);
  const int idx = (int)order_f[(size_t)b * NPTS + k];
  const float4* src = (const float4*)(feat + ((size_t)b * NPTS + idx) * DIM);
  float4* dst = (float4*)(out + ((size_t)b * NPTS + k) * DIM);
  dst[threadIdx.x] = src[threadIdx.x];
}

extern "C" void kernel_launch(void* const* d_in, const int* in_sizes, int n_in,
                              void* d_out, int out_size, void* d_ws, size_t ws_size,
                              hipStream_t stream) {
  const float* features = (const float*)d_in[0];
  const float* coords   = (const float*)d_in[1];
  float* out = (float*)d_out;
  float* order_f = out + (size_t)BATCH * NPTS * DIM;

  static bool attr_done = false;
  if (!attr_done) {
    (void)hipFuncSetAttribute((const void*)traverse_k,
                              hipFuncAttributeMaxDynamicSharedMemorySize, 131072);
    attr_done = true;
  }

  // ws per batch: rs (N*8) + S (N*N*4) + fn (N*D*4) + cand8 (N*8*8)  -> C=16
  const size_t per_b = (size_t)NPTS * 8 + (size_t)NPTS * NPTS * 4 +
                       (size_t)NPTS * DIM * 4 + (size_t)NPTS * 8 * 8;
  int C = BATCH;
  while (C > 1 && per_b * (size_t)C > ws_size) C >>= 1;

  char* wp = (char*)d_ws;
  double* rowsum = (double*)wp;               wp += (size_t)C * NPTS * 8;
  float*  S      = (float*)wp;                wp += (size_t)C * NPTS * NPTS * 4;
  float*  fn     = (float*)wp;                wp += (size_t)C * NPTS * DIM * 4;
  ull*    cand8  = (ull*)wp;

  for (int cs = 0; cs < BATCH; cs += C) {
    normalize_k<<<dim3(C * NPTS), dim3(256), 0, stream>>>(features, fn, cs);
    gemm_k<<<dim3(16, 16, C), dim3(512), 0, stream>>>(fn, coords, S, cs);
    mirror_k<<<dim3(32, 32, C), dim3(256), 0, stream>>>(S);
    cand_k<<<dim3(C * NPTS), dim3(64), 0, stream>>>(S, cand8, rowsum);
    traverse_k<<<dim3(C), dim3(64), 131072, stream>>>(S, cand8, rowsum, order_f, cs);
  }
  gather_k<<<dim3(BATCH * NPTS), dim3(192), 0, stream>>>(features, order_f, out);
}

// Round 17
// 1758.012 us; speedup vs baseline: 1.2572x; 1.0133x over previous
//
#include <hip/hip_runtime.h>
#include <math.h>

#define BATCH 16
#define NPTS  2048
#define DIM   768
#define NCH   24      // 768 / 32 k-chunks
#define PADW  40      // bf16 row stride within a plane

typedef unsigned long long ull;
typedef float f32x4 __attribute__((ext_vector_type(4)));
typedef short bf8 __attribute__((ext_vector_type(8)));          // 8 bf16 = 4 VGPR

// RNE fp32 -> bf16, bits with low 16 zeroed (== round-trip bit pattern)
__device__ __forceinline__ unsigned bfr(float x) {
  unsigned u = __float_as_uint(x);
  return (u + 0x7FFFu + ((u >> 16) & 1u)) & 0xFFFF0000u;
}
__device__ __forceinline__ unsigned short f2bf(float x) {
  unsigned u = __float_as_uint(x);
  u += 0x7FFFu + ((u >> 16) & 1u);
  return (unsigned short)(u >> 16);
}

// ---------------- normalize: fn = f / max(||f||,1e-12), fp64 norm (fp32 output) ----------------
__global__ void normalize_k(const float* __restrict__ feat, float* __restrict__ fn, int cs) {
  const int rn = blockIdx.x;                 // ci*NPTS + n
  const int ci = rn >> 11, n = rn & (NPTS - 1);
  const float* src = feat + ((size_t)(cs + ci) * NPTS + n) * DIM;
  const int t = threadIdx.x;                 // 256 threads
  float f0 = src[t], f1 = src[t + 256], f2 = src[t + 512];
  double s = (double)f0 * (double)f0 + (double)f1 * (double)f1 + (double)f2 * (double)f2;
  for (int off = 32; off > 0; off >>= 1) s += __shfl_down(s, off);
  __shared__ double ps[4];
  __shared__ double rbc;
  const int lane = t & 63, wid = t >> 6;
  if (lane == 0) ps[wid] = s;
  __syncthreads();
  if (t == 0) {
    double tot = ps[0] + ps[1] + ps[2] + ps[3];
    rbc = fmax(sqrt(tot), 1e-12);
  }
  __syncthreads();
  const double r = rbc;
  float* dst = fn + ((size_t)ci * NPTS + n) * DIM;
  dst[t]       = (float)((double)f0 / r);
  dst[t + 256] = (float)((double)f1 / r);
  dst[t + 512] = (float)((double)f2 / r);
}

// ---------------- similarity: S = fn.fn^T via split-3 bf16 MFMA + 0.5*exp(-d2/1e4) ------------
// Upper-triangle 128x128 tiles (bx<=by); mirror_k fills the rest.
// Round-16/17: 1024 threads / 16 waves per block, each wave owns a 32x32 sub-tile (2x2 MFMA
// tiles). Round-15 proved wave-parallelism is the lever (4->8 waves: 963->796us) and that
// the next step was register-capped (84 VGPR + 96 acc = 180/wave -> only 2 waves/SIMD).
// 32x32 tiles shrink per-wave state to ~110-125 regs (acc 48 + B-frags 24 + A-frags 12
// per-tr + staging 8) <= 128, so all 16 waves co-reside -> 4 waves/SIMD, and per-wave
// serial MFMA halves to 24/chunk. Each output element keeps its own hi/mid/lo k-ascending
// MFMA chains (only wave ownership changes) -> S BIT-IDENTICAL to rounds 9/15.
__global__ __launch_bounds__(1024, 1) void gemm_k(const float* __restrict__ fn,
                                                  const float* __restrict__ coords,
                                                  float* __restrict__ S, int cs) {
  if (blockIdx.x > blockIdx.y) return;       // symmetry: skip strictly-lower tiles
  const int ci = blockIdx.z;
  const int i0 = blockIdx.x * 128;
  const int j0 = blockIdx.y * 128;
  const int tid  = threadIdx.x;              // 1024
  const int lane = tid & 63, w = tid >> 6;   // 16 waves
  const int wrow = (w >> 2) * 32, wcol = (w & 3) * 32;   // wave sub-tile origin (4x4 grid)
  const int lo = lane & 15, quad = lane >> 4;

  __shared__ unsigned short At[3][128][PADW]; // 30720 B
  __shared__ unsigned short Bt[3][128][PADW]; // 30720 B

  f32x4 aH[2][2], aM[2][2], aL[2][2];
#pragma unroll
  for (int tr = 0; tr < 2; ++tr)
#pragma unroll
    for (int tc = 0; tc < 2; ++tc) {
      aH[tr][tc] = (f32x4){0.f, 0.f, 0.f, 0.f};
      aM[tr][tc] = (f32x4){0.f, 0.f, 0.f, 0.f};
      aL[tr][tc] = (f32x4){0.f, 0.f, 0.f, 0.f};
    }

  const float* fb = fn + (size_t)ci * NPTS * DIM;
  const int row = tid >> 3;                  // staging row 0..127 (8 threads/row)
  const int q   = tid & 7;                   // 4-float sub-band of the k32 chunk
  const float* ag = fb + (size_t)(i0 + row) * DIM + q * 4;
  const float* bg = fb + (size_t)(j0 + row) * DIM + q * 4;

  float4 fa, fv;
  // prefetch chunk 0
  fa = *(const float4*)(ag);
  fv = *(const float4*)(bg);

#pragma unroll 1
  for (int c = 0; c < NCH; ++c) {
    __syncthreads();               // previous chunk's readers done
    // ---- convert 4 elems/matrix -> split-3 planes, write (same formula/layout as r9) ----
    {
      float wa[4] = { fa.x, fa.y, fa.z, fa.w };
      float wb[4] = { fv.x, fv.y, fv.z, fv.w };
      unsigned sa[3][2], sb[3][2];
#pragma unroll
      for (int j = 0; j < 4; j += 2) {
        {
          float w0 = wa[j], w1 = wa[j + 1];
          unsigned a0 = bfr(w0); float r0 = w0 - __uint_as_float(a0);
          unsigned a1 = bfr(w1); float r1 = w1 - __uint_as_float(a1);
          unsigned b0 = bfr(r0); float q0 = r0 - __uint_as_float(b0);
          unsigned b1 = bfr(r1); float q1 = r1 - __uint_as_float(b1);
          sa[0][j >> 1] = (a0 >> 16) | (a1 & 0xFFFF0000u);
          sa[1][j >> 1] = (b0 >> 16) | (b1 & 0xFFFF0000u);
          sa[2][j >> 1] = (bfr(q0) >> 16) | (bfr(q1) & 0xFFFF0000u);
        }
        {
          float w0 = wb[j], w1 = wb[j + 1];
          unsigned a0 = bfr(w0); float r0 = w0 - __uint_as_float(a0);
          unsigned a1 = bfr(w1); float r1 = w1 - __uint_as_float(a1);
          unsigned b0 = bfr(r0); float q0 = r0 - __uint_as_float(b0);
          unsigned b1 = bfr(r1); float q1 = r1 - __uint_as_float(b1);
          sb[0][j >> 1] = (a0 >> 16) | (a1 & 0xFFFF0000u);
          sb[1][j >> 1] = (b0 >> 16) | (b1 & 0xFFFF0000u);
          sb[2][j >> 1] = (bfr(q0) >> 16) | (bfr(q1) & 0xFFFF0000u);
        }
      }
#pragma unroll
      for (int pl = 0; pl < 3; ++pl) {
        *(uint2*)&At[pl][row][q * 4] = *(const uint2*)&sa[pl][0];
        *(uint2*)&Bt[pl][row][q * 4] = *(const uint2*)&sb[pl][0];
      }
    }
    __syncthreads();
    if (c + 1 < NCH) {             // prefetch next chunk; overlaps MFMA below
      const int kc = (c + 1) * 32;
      fa = *(const float4*)(ag + kc);
      fv = *(const float4*)(bg + kc);
    }
    // B fragments (24 regs live), then per-tr A fragments (12 regs) -> low pressure
    bf8 B0[2], B1[2], B2[2];
#pragma unroll
    for (int t = 0; t < 2; ++t) {
      const int rB = wcol + t * 16 + lo, k8 = quad * 8;
      B0[t] = *(const bf8*)&Bt[0][rB][k8];
      B1[t] = *(const bf8*)&Bt[1][rB][k8];
      B2[t] = *(const bf8*)&Bt[2][rB][k8];
    }
#pragma unroll
    for (int tr = 0; tr < 2; ++tr) {
      const int rA = wrow + tr * 16 + lo, k8 = quad * 8;
      bf8 A0 = *(const bf8*)&At[0][rA][k8];
      bf8 A1 = *(const bf8*)&At[1][rA][k8];
      bf8 A2 = *(const bf8*)&At[2][rA][k8];
#pragma unroll
      for (int tc = 0; tc < 2; ++tc) {
        aH[tr][tc] = __builtin_amdgcn_mfma_f32_16x16x32_bf16(A0, B0[tc], aH[tr][tc], 0, 0, 0);
        aM[tr][tc] = __builtin_amdgcn_mfma_f32_16x16x32_bf16(A0, B1[tc], aM[tr][tc], 0, 0, 0);
        aM[tr][tc] = __builtin_amdgcn_mfma_f32_16x16x32_bf16(A1, B0[tc], aM[tr][tc], 0, 0, 0);
        aL[tr][tc] = __builtin_amdgcn_mfma_f32_16x16x32_bf16(A0, B2[tc], aL[tr][tc], 0, 0, 0);
        aL[tr][tc] = __builtin_amdgcn_mfma_f32_16x16x32_bf16(A1, B1[tc], aL[tr][tc], 0, 0, 0);
        aL[tr][tc] = __builtin_amdgcn_mfma_f32_16x16x32_bf16(A2, B0[tc], aL[tr][tc], 0, 0, 0);
      }
    }
  }

  // ---- probe the true C/D slot->(row,col) mapping (exact small ints in bf16/fp32) ----
  {
    const unsigned short encv = f2bf((float)lo);
    const unsigned short onev = f2bf(1.0f);
    bf8 enc, one;
#pragma unroll
    for (int t = 0; t < 8; ++t) { enc[t] = (short)encv; one[t] = (short)onev; }
    f32x4 z = (f32x4){0.f, 0.f, 0.f, 0.f};
    f32x4 d1 = __builtin_amdgcn_mfma_f32_16x16x32_bf16(enc, one, z, 0, 0, 0); // = 32*row
    f32x4 d2 = __builtin_amdgcn_mfma_f32_16x16x32_bf16(one, enc, z, 0, 0, 0); // = 32*col
    int rowp[4], colp[4];
#pragma unroll
    for (int r = 0; r < 4; ++r) {
      rowp[r] = ((int)(d1[r] * (1.0f / 32.0f))) & 15;
      colp[r] = ((int)(d2[r] * (1.0f / 32.0f))) & 15;
    }

    // epilogue: S = hi+mid+lo (fp64 sum) + 0.5*exp(-d2/1e4) (4th-order Taylor, exact regime)
    const float* cb = coords + (size_t)(cs + ci) * NPTS * 2;
    float* Sb = S + (size_t)ci * NPTS * NPTS;
#pragma unroll
    for (int r = 0; r < 4; ++r) {
      const int rl = rowp[r], cl = colp[r];
#pragma unroll
      for (int tr = 0; tr < 2; ++tr) {
        const int rowi = i0 + wrow + tr * 16 + rl;
        float2 pi = *(const float2*)(cb + 2 * rowi);
        const double cix = pi.x, ciy = pi.y;
#pragma unroll
        for (int tc = 0; tc < 2; ++tc) {
          const int colj = j0 + wcol + tc * 16 + cl;
          float2 pj = *(const float2*)(cb + 2 * colj);
          double dx = cix - (double)pj.x, dy = ciy - (double)pj.y;
          double x = (dx * dx + dy * dy) * (1.0 / 10000.0);
          double e = 1.0 - x * (1.0 - x * (0.5 - x * ((1.0 / 6.0) - x * (1.0 / 24.0))));
          double sem = (double)aH[tr][tc][r] + (double)aM[tr][tc][r] + (double)aL[tr][tc][r];
          Sb[(size_t)rowi * NPTS + colj] = (float)(sem + 0.5 * e);
        }
      }
    }
  }
}

// ---------------- mirror: fill strictly-lower 128-blocks from upper triangle ----------------
__global__ __launch_bounds__(256) void mirror_k(float* __restrict__ S) {
  const int Cb = blockIdx.x, Rb = blockIdx.y;
  if ((Rb >> 1) <= (Cb >> 1)) return;
  float* Sb = S + (size_t)blockIdx.z * NPTS * NPTS;
  __shared__ float t[64][65];
  const int lane = threadIdx.x & 63, w = threadIdx.x >> 6;
#pragma unroll
  for (int p = 0; p < 16; ++p) {
    const int r = w + 4 * p;
    t[r][lane] = Sb[(size_t)(Cb * 64 + r) * NPTS + Rb * 64 + lane];
  }
  __syncthreads();
#pragma unroll
  for (int p = 0; p < 16; ++p) {
    const int r = w + 4 * p;
    Sb[(size_t)(Rb * 64 + r) * NPTS + Cb * 64 + lane] = t[lane][r];
  }
}

// ---------------- monotone fp32 key ----------------
__device__ __forceinline__ unsigned mono(float f) {
  unsigned u = __float_as_uint(f);
  return (u & 0x80000000u) ? ~u : (u | 0x80000000u);
}

// ---------------- packed u64 DPP max step ----------------
#define DPP64_STEP(X, CTRL, RMASK) do {                                                   \
  unsigned lo_ = (unsigned)(X), hi_ = (unsigned)((X) >> 32);                              \
  unsigned lo2_ = (unsigned)__builtin_amdgcn_update_dpp((int)lo_, (int)lo_, CTRL, RMASK, 0xf, false); \
  unsigned hi2_ = (unsigned)__builtin_amdgcn_update_dpp((int)hi_, (int)hi_, CTRL, RMASK, 0xf, false); \
  ull o_ = ((ull)hi2_ << 32) | lo2_;                                                      \
  if (o_ > (X)) (X) = o_;                                                                 \
} while (0)

// full 64-lane argmax (slow path / start node)
__device__ __forceinline__ ull wave_amax64(ull x) {
  DPP64_STEP(x, 0x111, 0xf);
  DPP64_STEP(x, 0x112, 0xf);
  DPP64_STEP(x, 0x114, 0xf);
  DPP64_STEP(x, 0x118, 0xf);
  DPP64_STEP(x, 0x142, 0xa);
  DPP64_STEP(x, 0x143, 0xc);
  unsigned lo = (unsigned)__builtin_amdgcn_readlane((int)(unsigned)x, 63);
  unsigned hi = (unsigned)__builtin_amdgcn_readlane((int)(unsigned)(x >> 32), 63);
  return ((ull)hi << 32) | lo;
}

// ---------------- cand_k: exact top-7 + tau(=8th max) per row + fp64 rowsum ----------------
__global__ __launch_bounds__(64) void cand_k(const float* __restrict__ S,
                                             ull* __restrict__ cand8,
                                             double* __restrict__ rs) {
  const size_t r = blockIdx.x;               // ci*NPTS + row
  const int row = (int)(r & (NPTS - 1));
  const float* rowp = S + r * NPTS;
  const int lane = threadIdx.x;

  float4 q[8];
  double sum = 0.0;
#pragma unroll
  for (int c = 0; c < 8; ++c) {
    q[c] = ((const float4*)rowp)[c * 64 + lane];
    sum += (double)q[c].x; sum += (double)q[c].y; sum += (double)q[c].z; sum += (double)q[c].w;
  }
  {
    double s2 = sum;
    for (int off = 32; off > 0; off >>= 1) s2 += __shfl_down(s2, off);
    if (lane == 0) rs[r] = s2;
  }

  unsigned rem = 0;
  const int dd = row - 4 * lane;
  if (dd >= 0 && dd < 2048 && (dd & 0xFC) == 0) rem = 1u << (((dd >> 8) << 2) | (dd & 3));

  float bv; int bp;
  auto rescan = [&]() {
    bv = -INFINITY; bp = 0;
#pragma unroll
    for (int c = 0; c < 8; ++c) {
      const float xs0 = q[c].x, xs1 = q[c].y, xs2 = q[c].z, xs3 = q[c].w;
      float x0 = ((rem >> (4 * c + 0)) & 1u) ? -INFINITY : xs0;
      float x1 = ((rem >> (4 * c + 1)) & 1u) ? -INFINITY : xs1;
      float x2 = ((rem >> (4 * c + 2)) & 1u) ? -INFINITY : xs2;
      float x3 = ((rem >> (4 * c + 3)) & 1u) ? -INFINITY : xs3;
      if (x0 > bv) { bv = x0; bp = 4 * c + 0; }
      if (x1 > bv) { bv = x1; bp = 4 * c + 1; }
      if (x2 > bv) { bv = x2; bp = 4 * c + 2; }
      if (x3 > bv) { bv = x3; bp = 4 * c + 3; }
    }
  };
  rescan();

#pragma unroll 1
  for (int rnd = 0; rnd < 8; ++rnd) {
    const int gi = ((bp >> 2) << 8) + 4 * lane + (bp & 3);
    const ull pk = ((ull)mono(bv) << 32) | (unsigned)(2047 - gi);
    const ull red = wave_amax64(pk);
    if (rnd < 7) {
      if (lane == 0) cand8[r * 8 + rnd] = red;
      if (pk == red) { rem |= 1u << bp; rescan(); }
    } else {
      if (lane == 0) cand8[r * 8 + 7] = (red >> 32) << 32;
    }
  }
}

// ---------------- greedy traversal: LDS candidate table, no speculative prefetch ----------------
__global__ __launch_bounds__(64) void traverse_k(const float* __restrict__ S,
                                                 const ull* __restrict__ cand8,
                                                 const double* __restrict__ rs,
                                                 float* __restrict__ order_f, int cs) {
  extern __shared__ ull tabL[];              // [NPTS*8]
  const int ci = blockIdx.x;
  const int gb = cs + ci;
  const int lane = threadIdx.x;

  {
    float4* ls = (float4*)tabL;
    const float4* gs = (const float4*)(cand8 + (size_t)ci * NPTS * 8);
#pragma unroll 1
    for (int i0 = 0; i0 < 8192; i0 += 512) {
      float4 t[8];
#pragma unroll
      for (int j = 0; j < 8; ++j) t[j] = gs[i0 + j * 64 + lane];
#pragma unroll
      for (int j = 0; j < 8; ++j) ls[i0 + j * 64 + lane] = t[j];
    }
  }
  __syncthreads();

  // start node: argmax of fp64 rowsum (tie -> min index)
  const double* rb = rs + (size_t)ci * NPTS;
  double dv = -1.0e300; int di = 0;
#pragma unroll
  for (int c = 0; c < 32; ++c) {
    int j = c * 64 + lane;
    double v = rb[j];
    if (v > dv) { dv = v; di = j; }
  }
  for (int off = 32; off > 0; off >>= 1) {
    double vo = __shfl_down(dv, off);
    int io = __shfl_down(di, off);
    if (vo > dv || (vo == dv && io < di)) { dv = vo; di = io; }
  }
  int cur = __shfl(di, 0);

  unsigned vis = 0, visw = 0;
  if (lane == ((cur >> 2) & 63)) vis |= 1u << (((cur >> 8) << 2) | (cur & 3));
  if (lane == (cur >> 5))        visw |= 1u << (cur & 31);
  if (lane == 0) order_f[(size_t)gb * NPTS] = (float)cur;

  const float* Sb = S + (size_t)ci * NPTS * NPTS;
  const int slot = lane & 7;

#pragma unroll 1
  for (int s = 1; s < NPTS; ++s) {
    const ull e = tabL[cur * 8 + slot];                       // broadcast ds_read_b64
    const unsigned idx = 2047u - (unsigned)(e & 0xFFFFFFFFu);
    const unsigned wv = (unsigned)__shfl((int)visw, (int)(idx >> 5));
    ull mk = ((slot == 7) || ((wv >> (idx & 31)) & 1u)) ? 0ull : e;
    DPP64_STEP(mk, 0x111, 0xf);   // row_shr:1
    DPP64_STEP(mk, 0x112, 0xf);   // row_shr:2
    DPP64_STEP(mk, 0x114, 0xf);   // row_shr:4
    const unsigned kH = (unsigned)__builtin_amdgcn_readlane((int)(unsigned)(mk >> 32), 7);
    const unsigned kL = (unsigned)__builtin_amdgcn_readlane((int)(unsigned)mk, 7);
    const unsigned tH = (unsigned)__builtin_amdgcn_readlane((int)(unsigned)(e >> 32), 7);
    int nxt;
    if (kH > tH) {
      nxt = (int)(2047u - kL);
    } else {
      // slow path: load + scan the full S row (uniform branch)
      const float4* rowp = (const float4*)(Sb + (size_t)cur * NPTS);
      float4 v[8];
#pragma unroll
      for (int c = 0; c < 8; ++c) v[c] = rowp[c * 64 + lane];
      float bvv = -INFINITY; int bi = 0;
#pragma unroll
      for (int c = 0; c < 8; ++c) {
        const int base = c * 256 + 4 * lane;
        float x0 = (vis & (1u << (4 * c + 0))) ? -INFINITY : v[c].x;
        float x1 = (vis & (1u << (4 * c + 1))) ? -INFINITY : v[c].y;
        float x2 = (vis & (1u << (4 * c + 2))) ? -INFINITY : v[c].z;
        float x3 = (vis & (1u << (4 * c + 3))) ? -INFINITY : v[c].w;
        if (x0 > bvv) { bvv = x0; bi = base + 0; }
        if (x1 > bvv) { bvv = x1; bi = base + 1; }
        if (x2 > bvv) { bvv = x2; bi = base + 2; }
        if (x3 > bvv) { bvv = x3; bi = base + 3; }
      }
      const ull pk = ((ull)mono(bvv) << 32) | (unsigned)(2047 - bi);
      const ull mm = wave_amax64(pk);
      nxt = (int)(2047u - (unsigned)(mm & 0xFFFFFFFFu));
    }
    if (lane == ((nxt >> 2) & 63)) vis |= 1u << (((nxt >> 8) << 2) | (nxt & 3));
    if (lane == (nxt >> 5))        visw |= 1u << (nxt & 31);
    if (lane == 0) order_f[(size_t)gb * NPTS + s] = (float)nxt;
    cur = nxt;
  }
}

// ---------------- gather: reordered = features[order] ----------------
__global__ void gather_k(const float* __restrict__ feat, const float* __restrict__ order_f,
                         float* __restrict__ out) {
  const int bk = blockIdx.x;
  const int b = bk >> 11, k = bk & (NPTS - 1);
  const int idx = (int)order_f[(size_t)b * NPTS + k];
  const float4* src = (const float4*)(feat + ((size_t)b * NPTS + idx) * DIM);
  float4* dst = (float4*)(out + ((size_t)b * NPTS + k) * DIM);
  dst[threadIdx.x] = src[threadIdx.x];
}

extern "C" void kernel_launch(void* const* d_in, const int* in_sizes, int n_in,
                              void* d_out, int out_size, void* d_ws, size_t ws_size,
                              hipStream_t stream) {
  const float* features = (const float*)d_in[0];
  const float* coords   = (const float*)d_in[1];
  float* out = (float*)d_out;
  float* order_f = out + (size_t)BATCH * NPTS * DIM;

  static bool attr_done = false;
  if (!attr_done) {
    (void)hipFuncSetAttribute((const void*)traverse_k,
                              hipFuncAttributeMaxDynamicSharedMemorySize, 131072);
    attr_done = true;
  }

  // ws per batch: rs (N*8) + S (N*N*4) + fn (N*D*4) + cand8 (N*8*8)  -> C=16
  const size_t per_b = (size_t)NPTS * 8 + (size_t)NPTS * NPTS * 4 +
                       (size_t)NPTS * DIM * 4 + (size_t)NPTS * 8 * 8;
  int C = BATCH;
  while (C > 1 && per_b * (size_t)C > ws_size) C >>= 1;

  char* wp = (char*)d_ws;
  double* rowsum = (double*)wp;               wp += (size_t)C * NPTS * 8;
  float*  S      = (float*)wp;                wp += (size_t)C * NPTS * NPTS * 4;
  float*  fn     = (float*)wp;                wp += (size_t)C * NPTS * DIM * 4;
  ull*    cand8  = (ull*)wp;

  for (int cs = 0; cs < BATCH; cs += C) {
    normalize_k<<<dim3(C * NPTS), dim3(256), 0, stream>>>(features, fn, cs);
    gemm_k<<<dim3(16, 16, C), dim3(1024), 0, stream>>>(fn, coords, S, cs);
    mirror_k<<<dim3(32, 32, C), dim3(256), 0, stream>>>(S);
    cand_k<<<dim3(C * NPTS), dim3(64), 0, stream>>>(S, cand8, rowsum);
    traverse_k<<<dim3(C), dim3(64), 131072, stream>>>(S, cand8, rowsum, order_f, cs);
  }
  gather_k<<<dim3(BATCH * NPTS), dim3(192), 0, stream>>>(features, order_f, out);
}